// Round 1
// baseline (357.700 us; speedup 1.0000x reference)
//
#include <hip/hip_runtime.h>
#include <hip/hip_bf16.h>

// Problem constants
// B=2, C=32, N=4, V=32, W=32, E=256, H=8, D=32, K_H=K_W=7
// L = V*W = 1024, Bn = B*N = 8, M = L*Bn = 8192
#define M_ROWS 8192
#define E_DIM 256

// ---------------------------------------------------------------------------
// K1: fused gather + input projection (C=32 -> E=256) + dual LayerNorm
// 4 rows per block, 256 threads (thread = output channel e)
// ---------------------------------------------------------------------------
__global__ __launch_bounds__(256) void embed_ln_kernel(
    const float* __restrict__ x_lf, const float* __restrict__ x_hf,
    const float* __restrict__ w_in, const float* __restrict__ w_qk,
    const float* __restrict__ ln_g, const float* __restrict__ ln_b,
    float* __restrict__ epi_tok, float* __restrict__ epi_kv,
    float* __restrict__ q_in, float* __restrict__ k_in)
{
    int m0 = blockIdx.x * 4;
    int tid = threadIdx.x;
    __shared__ float xs[4][64];   // [row][0..31]=x_lf chans, [32..63]=x_hf chans

    {
        int r = tid >> 6;          // 0..3
        int idx = tid & 63;        // 0..63
        int m = m0 + r;
        int l = m >> 3, bn = m & 7;
        int bb = bn >> 2, nn = bn & 3;
        int vv = l >> 5, ww = l & 31;
        int base = bb * 131072 + nn * 1024 + vv * 32 + ww;  // + c*4096
        int c = idx & 31;
        float val = (idx < 32) ? x_lf[base + c * 4096] : x_hf[base + c * 4096];
        xs[r][idx] = val;
    }
    __syncthreads();

    int e = tid;
    float at[4] = {0.f, 0.f, 0.f, 0.f};
    float ak[4] = {0.f, 0.f, 0.f, 0.f};
#pragma unroll
    for (int c = 0; c < 32; ++c) {
        float wi = w_in[e * 32 + c];
        float wq = w_qk[e * 32 + c];
#pragma unroll
        for (int r = 0; r < 4; ++r) {
            at[r] += xs[r][c] * wi;
            ak[r] += xs[r][32 + c] * wq;
        }
    }

    __shared__ float part[4][4][4];  // [wave][row][{s_t,q_t,s_k,q_k}]
    int wv = tid >> 6;
#pragma unroll
    for (int r = 0; r < 4; ++r) {
        float s1 = at[r], q1 = at[r] * at[r];
        float s2 = ak[r], q2 = ak[r] * ak[r];
        for (int off = 32; off; off >>= 1) {
            s1 += __shfl_xor(s1, off);
            q1 += __shfl_xor(q1, off);
            s2 += __shfl_xor(s2, off);
            q2 += __shfl_xor(q2, off);
        }
        if ((tid & 63) == 0) {
            part[wv][r][0] = s1; part[wv][r][1] = q1;
            part[wv][r][2] = s2; part[wv][r][3] = q2;
        }
    }
    __syncthreads();

    float gg = ln_g[e], bv = ln_b[e];
#pragma unroll
    for (int r = 0; r < 4; ++r) {
        float S1 = part[0][r][0] + part[1][r][0] + part[2][r][0] + part[3][r][0];
        float Q1 = part[0][r][1] + part[1][r][1] + part[2][r][1] + part[3][r][1];
        float S2 = part[0][r][2] + part[1][r][2] + part[2][r][2] + part[3][r][2];
        float Q2 = part[0][r][3] + part[1][r][3] + part[2][r][3] + part[3][r][3];
        float mu1 = S1 * (1.f / 256.f), mu2 = S2 * (1.f / 256.f);
        float rs1 = rsqrtf(Q1 * (1.f / 256.f) - mu1 * mu1 + 1e-5f);
        float rs2 = rsqrtf(Q2 * (1.f / 256.f) - mu2 * mu2 + 1e-5f);
        int m = m0 + r;
        epi_tok[m * 256 + e] = at[r];
        epi_kv[m * 256 + e] = ak[r];
        q_in[m * 256 + e] = (at[r] - mu1) * rs1 * gg + bv;
        k_in[m * 256 + e] = (ak[r] - mu2) * rs2 * gg + bv;
    }
}

// ---------------------------------------------------------------------------
// Generic 64x64-tile fp32 GEMM:  OUT[m,j] = act( sum_k A[m,k]*W[j,k] (+RES) )
// OUTMAP 0: plain row-major MxN.  OUTMAP 1: QKV head layout (Bn,H,L,D).
// grid.z used only for QKV (selects A operand / W slice / OUT slice).
// ---------------------------------------------------------------------------
template <int OUTMAP, bool RELU>
__global__ __launch_bounds__(256) void gemm64(
    const float* __restrict__ A0, const float* __restrict__ A1,
    const float* __restrict__ A2, const float* __restrict__ Wb,
    float* __restrict__ OUTb, const float* __restrict__ RES,
    int K, int N)
{
    int z = blockIdx.z;
    const float* A = (z == 0) ? A0 : (z == 1) ? A1 : A2;
    const float* W = Wb + (size_t)z * 65536;      // E*E per slice (QKV only)
    float* OUT = OUTb + (size_t)z * 2097152;      // M*E per slice (QKV only)

    __shared__ float As[64][36];
    __shared__ float Ws[64][36];

    int tid = threadIdx.x;
    int tx = tid & 15, ty = tid >> 4;
    int m0 = blockIdx.x * 64;
    int n0 = blockIdx.y * 64;

    float acc[4][4] = {};

    for (int kc = 0; kc < K; kc += 32) {
        int r = tid >> 2, c = (tid & 3) * 8;
        {
            const float* src = A + (size_t)(m0 + r) * K + kc + c;
            float4 v0 = *(const float4*)(src);
            float4 v1 = *(const float4*)(src + 4);
            *(float4*)&As[r][c] = v0;
            *(float4*)&As[r][c + 4] = v1;
        }
        {
            const float* src = W + (size_t)(n0 + r) * K + kc + c;
            float4 v0 = *(const float4*)(src);
            float4 v1 = *(const float4*)(src + 4);
            *(float4*)&Ws[r][c] = v0;
            *(float4*)&Ws[r][c + 4] = v1;
        }
        __syncthreads();
#pragma unroll
        for (int kk = 0; kk < 32; ++kk) {
            float a[4], w[4];
#pragma unroll
            for (int i = 0; i < 4; ++i) a[i] = As[ty + 16 * i][kk];
#pragma unroll
            for (int j = 0; j < 4; ++j) w[j] = Ws[tx + 16 * j][kk];
#pragma unroll
            for (int i = 0; i < 4; ++i)
#pragma unroll
                for (int j = 0; j < 4; ++j) acc[i][j] += a[i] * w[j];
        }
        __syncthreads();
    }

#pragma unroll
    for (int i = 0; i < 4; ++i) {
#pragma unroll
        for (int j = 0; j < 4; ++j) {
            int row = m0 + ty + 16 * i;
            int col = n0 + tx + 16 * j;
            float val = acc[i][j];
            if (RES) val += RES[(size_t)row * N + col];
            if (RELU) val = fmaxf(val, 0.f);
            if (OUTMAP == 0) {
                OUT[(size_t)row * N + col] = val;
            } else {
                int l = row >> 3, bn = row & 7;
                int h = col >> 5, d = col & 31;
                OUT[((bn * 8 + h) * 1024 + l) * 32 + d] = val;
            }
        }
    }
}

// ---------------------------------------------------------------------------
// K3: local-window attention. One wave per (bh, q). 49 keys max (7x7 window).
// Q/K/V layout: (Bn*H, L, D) contiguous.  ctx out: (L, Bn, E) row-major.
// ---------------------------------------------------------------------------
__global__ __launch_bounds__(256) void attn_kernel(
    const float* __restrict__ Qb, const float* __restrict__ Kb,
    const float* __restrict__ Vb, float* __restrict__ ctx)
{
    int wid = blockIdx.x * 4 + (threadIdx.x >> 6);
    int lane = threadIdx.x & 63;
    int bh = wid >> 10;          // 0..63  (= bn*8 + h)
    int q = wid & 1023;
    int qv = q >> 5, qw = q & 31;

    const float* Qr = Qb + ((size_t)bh * 1024 + q) * 32;

    float s = -1e30f;
    bool valid = false;
    if (lane < 49) {
        int kv = qv + lane / 7 - 3;
        int kw = qw + lane % 7 - 3;
        valid = (kv >= 0) && (kv < 32) && (kw >= 0) && (kw < 32);
        if (valid) {
            int lk = kv * 32 + kw;
            const float* Kr = Kb + ((size_t)bh * 1024 + lk) * 32;
            float acc = 0.f;
#pragma unroll
            for (int d = 0; d < 32; ++d) acc += Qr[d] * Kr[d];
            s = acc * 0.17677669529663687f;   // 1/sqrt(32)
        }
    }

    float mx = s;
    for (int off = 32; off; off >>= 1) mx = fmaxf(mx, __shfl_xor(mx, off));
    float ev = valid ? __expf(s - mx) : 0.f;
    float sum = ev;
    for (int off = 32; off; off >>= 1) sum += __shfl_xor(sum, off);
    float p = ev / sum;

    int d = lane & 31;
    float cacc = 0.f;
#pragma unroll
    for (int k = 0; k < 49; ++k) {
        float pk = __shfl(p, k);
        int kv = qv + k / 7 - 3;
        int kw = qw + k % 7 - 3;
        kv = min(max(kv, 0), 31);
        kw = min(max(kw, 0), 31);
        int l2 = kv * 32 + kw;
        cacc += pk * Vb[((size_t)bh * 1024 + l2) * 32 + d];
    }
    if (lane < 32) {
        int bn = bh >> 3, h = bh & 7;
        ctx[((size_t)q * 8 + bn) * 256 + h * 32 + d] = cacc;
    }
}

// ---------------------------------------------------------------------------
// K5: LayerNorm over E=256 (one row per block)
// ---------------------------------------------------------------------------
__global__ __launch_bounds__(256) void ln_kernel(
    const float* __restrict__ X, const float* __restrict__ g,
    const float* __restrict__ b, float* __restrict__ Y)
{
    int m = blockIdx.x;
    int e = threadIdx.x;
    float v = X[(size_t)m * 256 + e];
    float s = v, sq = v * v;
    for (int off = 32; off; off >>= 1) {
        s += __shfl_xor(s, off);
        sq += __shfl_xor(sq, off);
    }
    __shared__ float s4[4], q4[4];
    int wv = e >> 6;
    if ((e & 63) == 0) { s4[wv] = s; q4[wv] = sq; }
    __syncthreads();
    float S = s4[0] + s4[1] + s4[2] + s4[3];
    float SQ = q4[0] + q4[1] + q4[2] + q4[3];
    float mu = S * (1.f / 256.f);
    float rs = rsqrtf(SQ * (1.f / 256.f) - mu * mu + 1e-5f);
    Y[(size_t)m * 256 + e] = (v - mu) * rs * g[e] + b[e];
}

// ---------------------------------------------------------------------------
// K8: final E=256 -> C=32 projection with transposed store to (B,C,N,V,W)
// 8 rows per block; thread = (r = tid>>5, c = tid&31)
// ---------------------------------------------------------------------------
__global__ __launch_bounds__(256) void final_out_kernel(
    const float* __restrict__ A, const float* __restrict__ Wo,
    float* __restrict__ out)
{
    __shared__ float As[8][256];
    int m0 = blockIdx.x * 8;
    int tid = threadIdx.x;
#pragma unroll
    for (int i = 0; i < 8; ++i) {
        int idx = tid + i * 256;
        As[idx >> 8][idx & 255] = A[(size_t)(m0 + (idx >> 8)) * 256 + (idx & 255)];
    }
    __syncthreads();
    int r = tid >> 5, c = tid & 31;
    const float4* wrow = (const float4*)(Wo + c * 256);
    const float4* arow = (const float4*)(&As[r][0]);
    float acc = 0.f;
#pragma unroll
    for (int e4 = 0; e4 < 64; ++e4) {
        float4 a = arow[e4];
        float4 w = wrow[e4];
        acc += a.x * w.x + a.y * w.y + a.z * w.z + a.w * w.w;
    }
    int m = m0 + r;
    int l = m >> 3, bn = m & 7;
    int b = bn >> 2, n = bn & 3;
    int v = l >> 5, w = l & 31;
    out[(((b * 32 + c) * 4 + n) * 32 + v) * 32 + w] = acc;
}

// ---------------------------------------------------------------------------
extern "C" void kernel_launch(void* const* d_in, const int* in_sizes, int n_in,
                              void* d_out, int out_size, void* d_ws, size_t ws_size,
                              hipStream_t stream) {
    const float* x_lf       = (const float*)d_in[0];
    const float* x_hf       = (const float*)d_in[1];
    const float* w_in       = (const float*)d_in[2];
    const float* w_qk       = (const float*)d_in[3];
    const float* ln_g       = (const float*)d_in[4];
    const float* ln_b       = (const float*)d_in[5];
    const float* in_proj_w  = (const float*)d_in[6];
    const float* out_proj_w = (const float*)d_in[7];
    const float* ln2_g      = (const float*)d_in[8];
    const float* ln2_b      = (const float*)d_in[9];
    const float* ff_w1      = (const float*)d_in[10];
    const float* ff_w2      = (const float*)d_in[11];
    const float* w_out      = (const float*)d_in[12];
    float* out = (float*)d_out;

    float* ws = (float*)d_ws;
    float* epi_tok = ws + 0;            // M*E
    float* epi_kv  = ws + 2097152;      // M*E
    float* q_in    = ws + 4194304;      // M*E
    float* k_in    = ws + 6291456;      // M*E
    float* Qb      = ws + 8388608;      // M*E  (Bn,H,L,D)
    float* Kb      = ws + 10485760;     // M*E
    float* Vb      = ws + 12582912;     // M*E
    float* ctx     = q_in;              // reuse (q_in dead after QKV proj)
    float* ff_in   = k_in;              // reuse (k_in dead after QKV proj)
    float* ffh     = Qb;                // reuse Qb+Kb (dead after attention), M*512

    // 1. gather + input proj + dual LN
    embed_ln_kernel<<<2048, 256, 0, stream>>>(x_lf, x_hf, w_in, w_qk, ln_g, ln_b,
                                              epi_tok, epi_kv, q_in, k_in);
    // 2. QKV projection (z: 0=Q from q_in, 1=K from k_in, 2=V from epi_kv)
    gemm64<1, false><<<dim3(128, 4, 3), 256, 0, stream>>>(
        q_in, k_in, epi_kv, in_proj_w, Qb, nullptr, 256, 256);
    // 3. local-window attention
    attn_kernel<<<16384, 256, 0, stream>>>(Qb, Kb, Vb, ctx);
    // 4. out_proj + residual (in-place into epi_tok)
    gemm64<0, false><<<dim3(128, 4, 1), 256, 0, stream>>>(
        ctx, ctx, ctx, out_proj_w, epi_tok, epi_tok, 256, 256);
    // 5. LN2
    ln_kernel<<<8192, 256, 0, stream>>>(epi_tok, ln2_g, ln2_b, ff_in);
    // 6. FF1 + ReLU
    gemm64<0, true><<<dim3(128, 8, 1), 256, 0, stream>>>(
        ff_in, ff_in, ff_in, ff_w1, ffh, nullptr, 256, 512);
    // 7. FF2 + residual (in-place into epi_tok)
    gemm64<0, false><<<dim3(128, 4, 1), 256, 0, stream>>>(
        ffh, ffh, ffh, ff_w2, epi_tok, epi_tok, 512, 256);
    // 8. final projection + transposed store
    final_out_kernel<<<1024, 256, 0, stream>>>(epi_tok, w_out, out);
}

// Round 2
// 200.372 us; speedup vs baseline: 1.7852x; 1.7852x over previous
//
#include <hip/hip_runtime.h>
#include <hip/hip_bf16.h>

// Problem constants: B=2,C=32,N=4,V=32,W=32,E=256,H=8,D=32,K_H=K_W=7
// L=1024, Bn=8, M=8192

typedef __attribute__((ext_vector_type(8))) short short8v;   // 8 bf16 (4 VGPR)
typedef __attribute__((ext_vector_type(4))) float f32x4;

// round-to-nearest-even f32 -> bf16 bits (self-contained, no header type games)
__device__ __forceinline__ unsigned short f2bf(float x) {
    union { float f; unsigned u; } c; c.f = x;
    unsigned r = c.u + 0x7FFFu + ((c.u >> 16) & 1u);
    return (unsigned short)(r >> 16);
}

// ---------------------------------------------------------------------------
// K0: convert the four GEMM weight matrices fp32 -> bf16 bits
// concat sizes: in_proj 196608 | out_proj 65536 | ff_w1 131072 | ff_w2 131072
// ---------------------------------------------------------------------------
__global__ __launch_bounds__(256) void convw_kernel(
    const float* __restrict__ w1, const float* __restrict__ w2,
    const float* __restrict__ w3, const float* __restrict__ w4,
    unsigned short* __restrict__ o1, unsigned short* __restrict__ o2,
    unsigned short* __restrict__ o3, unsigned short* __restrict__ o4)
{
    int i = (blockIdx.x * 256 + threadIdx.x) * 4;   // 131072 threads x 4 = 524288
    const float* src; unsigned short* dst; int off;
    if (i < 196608)      { src = w1; dst = o1; off = i; }
    else if (i < 262144) { src = w2; dst = o2; off = i - 196608; }
    else if (i < 393216) { src = w3; dst = o3; off = i - 262144; }
    else                 { src = w4; dst = o4; off = i - 393216; }
    float4 v = *(const float4*)(src + off);
    ushort4 u;
    u.x = f2bf(v.x); u.y = f2bf(v.y); u.z = f2bf(v.z); u.w = f2bf(v.w);
    *(ushort4*)(dst + off) = u;
}

// ---------------------------------------------------------------------------
// K1: fused gather + input projection (C=32 -> E=256) + dual LayerNorm
// outputs: epi_tok fp32 (residual stream), kv_b / q_b / k_b bf16 (GEMM A)
// ---------------------------------------------------------------------------
__global__ __launch_bounds__(256) void embed_ln_kernel(
    const float* __restrict__ x_lf, const float* __restrict__ x_hf,
    const float* __restrict__ w_in, const float* __restrict__ w_qk,
    const float* __restrict__ ln_g, const float* __restrict__ ln_b,
    float* __restrict__ epi_tok, unsigned short* __restrict__ kv_b,
    unsigned short* __restrict__ q_b, unsigned short* __restrict__ k_b)
{
    int m0 = blockIdx.x * 4;
    int tid = threadIdx.x;
    __shared__ float xs[4][64];

    {
        int r = tid >> 6;
        int idx = tid & 63;
        int m = m0 + r;
        int l = m >> 3, bn = m & 7;
        int bb = bn >> 2, nn = bn & 3;
        int vv = l >> 5, ww = l & 31;
        int base = bb * 131072 + nn * 1024 + vv * 32 + ww;
        int c = idx & 31;
        xs[r][idx] = (idx < 32) ? x_lf[base + c * 4096] : x_hf[base + c * 4096];
    }
    __syncthreads();

    int e = tid;
    float at[4] = {0.f, 0.f, 0.f, 0.f};
    float ak[4] = {0.f, 0.f, 0.f, 0.f};
#pragma unroll
    for (int c = 0; c < 32; ++c) {
        float wi = w_in[e * 32 + c];
        float wq = w_qk[e * 32 + c];
#pragma unroll
        for (int r = 0; r < 4; ++r) {
            at[r] += xs[r][c] * wi;
            ak[r] += xs[r][32 + c] * wq;
        }
    }

    __shared__ float part[4][4][4];
    int wv = tid >> 6;
#pragma unroll
    for (int r = 0; r < 4; ++r) {
        float s1 = at[r], q1 = at[r] * at[r];
        float s2 = ak[r], q2 = ak[r] * ak[r];
        for (int off = 32; off; off >>= 1) {
            s1 += __shfl_xor(s1, off);
            q1 += __shfl_xor(q1, off);
            s2 += __shfl_xor(s2, off);
            q2 += __shfl_xor(q2, off);
        }
        if ((tid & 63) == 0) {
            part[wv][r][0] = s1; part[wv][r][1] = q1;
            part[wv][r][2] = s2; part[wv][r][3] = q2;
        }
    }
    __syncthreads();

    float gg = ln_g[e], bv = ln_b[e];
#pragma unroll
    for (int r = 0; r < 4; ++r) {
        float S1 = part[0][r][0] + part[1][r][0] + part[2][r][0] + part[3][r][0];
        float Q1 = part[0][r][1] + part[1][r][1] + part[2][r][1] + part[3][r][1];
        float S2 = part[0][r][2] + part[1][r][2] + part[2][r][2] + part[3][r][2];
        float Q2 = part[0][r][3] + part[1][r][3] + part[2][r][3] + part[3][r][3];
        float mu1 = S1 * (1.f / 256.f), mu2 = S2 * (1.f / 256.f);
        float rs1 = rsqrtf(Q1 * (1.f / 256.f) - mu1 * mu1 + 1e-5f);
        float rs2 = rsqrtf(Q2 * (1.f / 256.f) - mu2 * mu2 + 1e-5f);
        int m = m0 + r;
        epi_tok[m * 256 + e] = at[r];
        kv_b[m * 256 + e] = f2bf(ak[r]);
        q_b[m * 256 + e] = f2bf((at[r] - mu1) * rs1 * gg + bv);
        k_b[m * 256 + e] = f2bf((ak[r] - mu2) * rs2 * gg + bv);
    }
}

// ---------------------------------------------------------------------------
// K2: bf16 MFMA GEMM, 128x128 tile, 4 waves, BK=32.
// OUT[m,j] = act( sum_k A[m,k]*W[j,k] (+RES) )
// A: [M,K] bf16 row-major.  W: [N,K] bf16 row-major (B^T form).
// OUTMAP 0: row-major [M,N].  OUTMAP 1: QKV head layout (z slice, fp32).
// ---------------------------------------------------------------------------
template <int OUTMAP, bool RELU, bool OBF16>
__global__ __launch_bounds__(256) void gemm_mfma(
    const unsigned short* __restrict__ A0, const unsigned short* __restrict__ A1,
    const unsigned short* __restrict__ A2, const unsigned short* __restrict__ Wb,
    void* __restrict__ OUTv, const float* __restrict__ RES,
    int K, int N)
{
    int z = blockIdx.z;
    const unsigned short* A = (z == 0) ? A0 : (z == 1) ? A1 : A2;
    const unsigned short* W = Wb + (size_t)z * 65536;

    __shared__ unsigned short As[128 * 32];
    __shared__ unsigned short Ws[128 * 32];

    int tid = threadIdx.x;
    int lane = tid & 63, wid = tid >> 6;
    int wm = wid >> 1, wn = wid & 1;
    int m0 = blockIdx.x * 128, n0 = blockIdx.y * 128;

    f32x4 acc[4][4];
#pragma unroll
    for (int i = 0; i < 4; ++i)
#pragma unroll
        for (int j = 0; j < 4; ++j)
#pragma unroll
            for (int r = 0; r < 4; ++r) acc[i][j][r] = 0.f;

    int rA = lane & 15, k8r = lane >> 4;

    for (int kc = 0; kc < K; kc += 32) {
#pragma unroll
        for (int c = 0; c < 2; ++c) {
            int i = c * 256 + tid;          // chunk 0..511 (8 bf16 each)
            int row = i >> 2, k8 = i & 3;
            short8v va = *(const short8v*)(A + (size_t)(m0 + row) * K + kc + k8 * 8);
            short8v vw = *(const short8v*)(W + (size_t)(n0 + row) * K + kc + k8 * 8);
            *(short8v*)&As[i * 8] = va;
            *(short8v*)&Ws[i * 8] = vw;
        }
        __syncthreads();

        short8v a[4], b[4];
#pragma unroll
        for (int mi = 0; mi < 4; ++mi)
            a[mi] = *(const short8v*)&As[(wm * 64 + mi * 16 + rA) * 32 + k8r * 8];
#pragma unroll
        for (int ni = 0; ni < 4; ++ni)
            b[ni] = *(const short8v*)&Ws[(wn * 64 + ni * 16 + rA) * 32 + k8r * 8];
#pragma unroll
        for (int mi = 0; mi < 4; ++mi)
#pragma unroll
            for (int ni = 0; ni < 4; ++ni)
                acc[mi][ni] = __builtin_amdgcn_mfma_f32_16x16x32_bf16(
                    a[mi], b[ni], acc[mi][ni], 0, 0, 0);
        __syncthreads();
    }

#pragma unroll
    for (int mi = 0; mi < 4; ++mi) {
#pragma unroll
        for (int ni = 0; ni < 4; ++ni) {
#pragma unroll
            for (int r = 0; r < 4; ++r) {
                int row = m0 + wm * 64 + mi * 16 + (lane >> 4) * 4 + r;
                int col = n0 + wn * 64 + ni * 16 + (lane & 15);
                float v = acc[mi][ni][r];
                if (RES) v += RES[(size_t)row * N + col];
                if (RELU) v = fmaxf(v, 0.f);
                if (OUTMAP == 0) {
                    if (OBF16)
                        ((unsigned short*)OUTv)[(size_t)row * N + col] = f2bf(v);
                    else
                        ((float*)OUTv)[(size_t)row * N + col] = v;
                } else {
                    int l = row >> 3, bn = row & 7;
                    int h = col >> 5, d = col & 31;
                    ((float*)OUTv)[(size_t)z * 2097152 +
                                   ((bn * 8 + h) * 1024 + l) * 32 + d] = v;
                }
            }
        }
    }
}

// ---------------------------------------------------------------------------
// K3: local-window attention, block per (bh, qv): 32 queries, 7 K/V rows in LDS.
// 8 lanes per query; shfl softmax over the 8-lane group; xor-reduce PV.
// Writes ctx as bf16 (A operand of out_proj GEMM), layout (L,Bn,E).
// ---------------------------------------------------------------------------
__global__ __launch_bounds__(256) void attn_kernel(
    const float* __restrict__ Qb, const float* __restrict__ Kb,
    const float* __restrict__ Vb, unsigned short* __restrict__ ctx)
{
    int bh = blockIdx.x >> 5;       // 0..63  (bn*8+h)
    int qv = blockIdx.x & 31;
    int tid = threadIdx.x;

    __shared__ float Ks[7][32][36];
    __shared__ float Vs[7][32][36];   // 64512 B total

    // stage K/V rows [qv-3, qv+3] (clamped; invalid keys masked in scores)
#pragma unroll
    for (int it = 0; it < 7; ++it) {
        int idx = it * 256 + tid;      // 0..1791 float4s per tensor
        int dv = idx >> 8;             // 0..6
        int rem = idx & 255;
        int kw = rem >> 3, c = (rem & 7) * 4;
        int kvr = qv - 3 + dv;
        int kvc = min(max(kvr, 0), 31);
        size_t base = ((size_t)bh * 1024 + kvc * 32 + kw) * 32 + c;
        *(float4*)&Ks[dv][kw][c] = *(const float4*)(Kb + base);
        *(float4*)&Vs[dv][kw][c] = *(const float4*)(Vb + base);
    }

    int qq = tid >> 3, t = tid & 7;    // query-in-block, lane-in-query
    int q = qv * 32 + qq;

    // Q row into registers (L2-resident, broadcast across the 8 t-lanes)
    float4 qreg[8];
    {
        const float4* qp = (const float4*)(Qb + ((size_t)bh * 1024 + q) * 32);
#pragma unroll
        for (int d4 = 0; d4 < 8; ++d4) qreg[d4] = qp[d4];
    }
    __syncthreads();

    // this lane's keys: j = t + 8*jj
    float s[7];
    int kwj[7], dvj[7];
    bool val[7];
#pragma unroll
    for (int jj = 0; jj < 7; ++jj) {
        int j = t + 8 * jj;
        int dv = j / 7, dw = j % 7;
        int kvr = qv - 3 + dv, kwr = qq - 3 + dw;
        val[jj] = (j < 49) && (kvr >= 0) && (kvr < 32) && (kwr >= 0) && (kwr < 32);
        dvj[jj] = min(dv, 6);
        kwj[jj] = kwr & 31;
        s[jj] = 0.f;
    }

#pragma unroll
    for (int d4 = 0; d4 < 8; ++d4) {
        float4 qv4 = qreg[d4];
#pragma unroll
        for (int jj = 0; jj < 7; ++jj) {
            float4 k4 = *(const float4*)&Ks[dvj[jj]][kwj[jj]][d4 * 4];
            s[jj] += qv4.x * k4.x + qv4.y * k4.y + qv4.z * k4.z + qv4.w * k4.w;
        }
    }

    const float scale = 0.17677669529663687f;   // 1/sqrt(32)
    float mx = -1e30f;
#pragma unroll
    for (int jj = 0; jj < 7; ++jj) {
        s[jj] = val[jj] ? s[jj] * scale : -1e30f;
        mx = fmaxf(mx, s[jj]);
    }
    mx = fmaxf(mx, __shfl_xor(mx, 4));
    mx = fmaxf(mx, __shfl_xor(mx, 2));
    mx = fmaxf(mx, __shfl_xor(mx, 1));

    float e[7], sum = 0.f;
#pragma unroll
    for (int jj = 0; jj < 7; ++jj) { e[jj] = __expf(s[jj] - mx); sum += e[jj]; }
    sum += __shfl_xor(sum, 4);
    sum += __shfl_xor(sum, 2);
    sum += __shfl_xor(sum, 1);
    float inv = 1.f / sum;

    f32x4 acc[8];
#pragma unroll
    for (int d4 = 0; d4 < 8; ++d4)
#pragma unroll
        for (int i = 0; i < 4; ++i) acc[d4][i] = 0.f;

#pragma unroll
    for (int jj = 0; jj < 7; ++jj) {
        float p = e[jj] * inv;          // exactly 0 for invalid keys
#pragma unroll
        for (int d4 = 0; d4 < 8; ++d4) {
            float4 v4 = *(const float4*)&Vs[dvj[jj]][kwj[jj]][d4 * 4];
            acc[d4][0] += p * v4.x; acc[d4][1] += p * v4.y;
            acc[d4][2] += p * v4.z; acc[d4][3] += p * v4.w;
        }
    }

    // reduce partial PV across the 8 lanes of this query
#pragma unroll
    for (int off = 4; off; off >>= 1) {
#pragma unroll
        for (int d4 = 0; d4 < 8; ++d4) {
#pragma unroll
            for (int i = 0; i < 4; ++i)
                acc[d4][i] += __shfl_xor(acc[d4][i], off);
        }
    }

    // lane t writes d-slice [4t, 4t+4) as bf16
    {
        int bn = bh >> 3, h = bh & 7;
        unsigned short* dst = ctx + ((size_t)q * 8 + bn) * 256 + h * 32 + t * 4;
        ushort4 u;
        u.x = f2bf(acc[t][0]); u.y = f2bf(acc[t][1]);
        u.z = f2bf(acc[t][2]); u.w = f2bf(acc[t][3]);
        *(ushort4*)dst = u;
    }
}

// ---------------------------------------------------------------------------
// K5: LayerNorm over E=256, output bf16 (FF1 A operand)
// ---------------------------------------------------------------------------
__global__ __launch_bounds__(256) void ln_kernel(
    const float* __restrict__ X, const float* __restrict__ g,
    const float* __restrict__ b, unsigned short* __restrict__ Y)
{
    int m = blockIdx.x;
    int e = threadIdx.x;
    float v = X[(size_t)m * 256 + e];
    float s = v, sq = v * v;
    for (int off = 32; off; off >>= 1) {
        s += __shfl_xor(s, off);
        sq += __shfl_xor(sq, off);
    }
    __shared__ float s4[4], q4[4];
    int wv = e >> 6;
    if ((e & 63) == 0) { s4[wv] = s; q4[wv] = sq; }
    __syncthreads();
    float S = s4[0] + s4[1] + s4[2] + s4[3];
    float SQ = q4[0] + q4[1] + q4[2] + q4[3];
    float mu = S * (1.f / 256.f);
    float rs = rsqrtf(SQ * (1.f / 256.f) - mu * mu + 1e-5f);
    Y[(size_t)m * 256 + e] = f2bf((v - mu) * rs * g[e] + b[e]);
}

// ---------------------------------------------------------------------------
// K8: final E=256 -> C=32 projection with transposed store (fp32 throughout)
// ---------------------------------------------------------------------------
__global__ __launch_bounds__(256) void final_out_kernel(
    const float* __restrict__ A, const float* __restrict__ Wo,
    float* __restrict__ out)
{
    __shared__ float As[8][256];
    int m0 = blockIdx.x * 8;
    int tid = threadIdx.x;
#pragma unroll
    for (int i = 0; i < 8; ++i) {
        int idx = tid + i * 256;
        As[idx >> 8][idx & 255] = A[(size_t)(m0 + (idx >> 8)) * 256 + (idx & 255)];
    }
    __syncthreads();
    int r = tid >> 5, c = tid & 31;
    const float4* wrow = (const float4*)(Wo + c * 256);
    const float4* arow = (const float4*)(&As[r][0]);
    float acc = 0.f;
#pragma unroll
    for (int e4 = 0; e4 < 64; ++e4) {
        float4 a = arow[e4];
        float4 w = wrow[e4];
        acc += a.x * w.x + a.y * w.y + a.z * w.z + a.w * w.w;
    }
    int m = m0 + r;
    int l = m >> 3, bn = m & 7;
    int b = bn >> 2, n = bn & 3;
    int v = l >> 5, w = l & 31;
    out[(((b * 32 + c) * 4 + n) * 32 + v) * 32 + w] = acc;
}

// ---------------------------------------------------------------------------
extern "C" void kernel_launch(void* const* d_in, const int* in_sizes, int n_in,
                              void* d_out, int out_size, void* d_ws, size_t ws_size,
                              hipStream_t stream) {
    const float* x_lf       = (const float*)d_in[0];
    const float* x_hf       = (const float*)d_in[1];
    const float* w_in       = (const float*)d_in[2];
    const float* w_qk       = (const float*)d_in[3];
    const float* ln_g       = (const float*)d_in[4];
    const float* ln_b       = (const float*)d_in[5];
    const float* in_proj_w  = (const float*)d_in[6];
    const float* out_proj_w = (const float*)d_in[7];
    const float* ln2_g      = (const float*)d_in[8];
    const float* ln2_b      = (const float*)d_in[9];
    const float* ff_w1      = (const float*)d_in[10];
    const float* ff_w2      = (const float*)d_in[11];
    const float* w_out      = (const float*)d_in[12];
    float* out = (float*)d_out;

    char* w = (char*)d_ws;
    float* epi_tok  = (float*)(w);                       // 8 MB fp32 [8192,256]
    float* Qb       = (float*)(w + (8u  << 20));         // 8 MB (Bn,H,L,D)
    float* Kb       = (float*)(w + (16u << 20));         // contiguous with Qb
    float* Vb       = (float*)(w + (24u << 20));
    unsigned short* q_b    = (unsigned short*)(w + (32u << 20));  // 4 MB bf16
    unsigned short* k_b    = (unsigned short*)(w + (36u << 20));
    unsigned short* kv_b   = (unsigned short*)(w + (40u << 20));
    unsigned short* ctx_b  = (unsigned short*)(w + (44u << 20));
    unsigned short* ffin_b = (unsigned short*)(w + (48u << 20));
    unsigned short* ffh_b  = (unsigned short*)(w + (52u << 20));  // 8 MB [8192,512]
    unsigned short* wqkv_b = (unsigned short*)(w + (60u << 20));  // 384 KB
    unsigned short* wop_b  = (unsigned short*)(w + (61u << 20));  // 128 KB
    unsigned short* wff1_b = (unsigned short*)(w + (62u << 20));  // 256 KB
    unsigned short* wff2_b = (unsigned short*)(w + (63u << 20));  // 256 KB

    // 0. weights -> bf16
    convw_kernel<<<512, 256, 0, stream>>>(in_proj_w, out_proj_w, ff_w1, ff_w2,
                                          wqkv_b, wop_b, wff1_b, wff2_b);
    // 1. gather + input proj + dual LN
    embed_ln_kernel<<<2048, 256, 0, stream>>>(x_lf, x_hf, w_in, w_qk, ln_g, ln_b,
                                              epi_tok, kv_b, q_b, k_b);
    // 2. QKV projection (MFMA): z 0=Q(q_b) 1=K(k_b) 2=V(kv_b) -> (Bn,H,L,D) fp32
    gemm_mfma<1, false, false><<<dim3(64, 2, 3), 256, 0, stream>>>(
        q_b, k_b, kv_b, wqkv_b, (void*)Qb, nullptr, 256, 256);
    // 3. local-window attention -> ctx bf16
    attn_kernel<<<2048, 256, 0, stream>>>(Qb, Kb, Vb, ctx_b);
    // 4. out_proj + residual (epi_tok += ctx @ Wo^T)
    gemm_mfma<0, false, false><<<dim3(64, 2, 1), 256, 0, stream>>>(
        ctx_b, ctx_b, ctx_b, wop_b, (void*)epi_tok, epi_tok, 256, 256);
    // 5. LN2 -> bf16
    ln_kernel<<<8192, 256, 0, stream>>>(epi_tok, ln2_g, ln2_b, ffin_b);
    // 6. FF1 + ReLU -> bf16 [8192,512]
    gemm_mfma<0, true, true><<<dim3(64, 4, 1), 256, 0, stream>>>(
        ffin_b, ffin_b, ffin_b, wff1_b, (void*)ffh_b, nullptr, 256, 512);
    // 7. FF2 + residual (epi_tok += ffh @ W2^T)
    gemm_mfma<0, false, false><<<dim3(64, 2, 1), 256, 0, stream>>>(
        ffh_b, ffh_b, ffh_b, wff2_b, (void*)epi_tok, epi_tok, 512, 256);
    // 8. final projection + transposed store
    final_out_kernel<<<1024, 256, 0, stream>>>(epi_tok, w_out, out);
}

// Round 3
// 172.257 us; speedup vs baseline: 2.0765x; 1.1632x over previous
//
#include <hip/hip_runtime.h>
#include <hip/hip_bf16.h>

// Problem constants: B=2,C=32,N=4,V=32,W=32,E=256,H=8,D=32,K_H=K_W=7
// L=1024, Bn=8, M=8192.  Internal row ordering: m = bn*1024 + l  (bn-major)

typedef __attribute__((ext_vector_type(8))) short short8v;   // 8 bf16 (4 VGPR)
typedef __attribute__((ext_vector_type(4))) float f32x4;

__device__ __forceinline__ unsigned short f2bf(float x) {
    union { float f; unsigned u; } c; c.f = x;
    unsigned r = c.u + 0x7FFFu + ((c.u >> 16) & 1u);
    return (unsigned short)(r >> 16);
}

// ---------------------------------------------------------------------------
// K0: convert the four GEMM weight matrices fp32 -> bf16 bits
// ---------------------------------------------------------------------------
__global__ __launch_bounds__(256) void convw_kernel(
    const float* __restrict__ w1, const float* __restrict__ w2,
    const float* __restrict__ w3, const float* __restrict__ w4,
    unsigned short* __restrict__ o1, unsigned short* __restrict__ o2,
    unsigned short* __restrict__ o3, unsigned short* __restrict__ o4)
{
    int i = (blockIdx.x * 256 + threadIdx.x) * 4;
    const float* src; unsigned short* dst; int off;
    if (i < 196608)      { src = w1; dst = o1; off = i; }
    else if (i < 262144) { src = w2; dst = o2; off = i - 196608; }
    else if (i < 393216) { src = w3; dst = o3; off = i - 262144; }
    else                 { src = w4; dst = o4; off = i - 393216; }
    float4 v = *(const float4*)(src + off);
    ushort4 u;
    u.x = f2bf(v.x); u.y = f2bf(v.y); u.z = f2bf(v.z); u.w = f2bf(v.w);
    *(ushort4*)(dst + off) = u;
}

// ---------------------------------------------------------------------------
// K1: fused gather + input projection (MFMA, K=32) + dual LayerNorm
// Block: 64 rows (one bn, 64 consecutive l), 256 threads / 4 waves.
// Wave w owns rows w*16..w*16+15; 16 col-tiles cover E=256.
// outputs: epi_tok fp32 (residual), kv_b / q_b / k_b bf16.
// ---------------------------------------------------------------------------
__global__ __launch_bounds__(256) void embed_ln_mfma(
    const float* __restrict__ x_lf, const float* __restrict__ x_hf,
    const float* __restrict__ w_in, const float* __restrict__ w_qk,
    const float* __restrict__ ln_g, const float* __restrict__ ln_b,
    float* __restrict__ epi_tok, unsigned short* __restrict__ kv_b,
    unsigned short* __restrict__ q_b, unsigned short* __restrict__ k_b)
{
    __shared__ float xs[2][32][65];   // [tensor][c][l-local], pad 65 = xpose-safe

    int m0 = blockIdx.x * 64;
    int bn = m0 >> 10, l0 = m0 & 1023;
    int bb = bn >> 2, nn = bn & 3;
    int tid = threadIdx.x;

    // Phase A: coalesced load of both input tensors (64 l's x 32 channels)
    {
        int c = tid >> 3, i0 = (tid & 7) * 8;
        size_t base = (size_t)bb * 131072 + (size_t)c * 4096 + nn * 1024 + l0 + i0;
        float4 a0 = *(const float4*)(x_lf + base);
        float4 a1 = *(const float4*)(x_lf + base + 4);
        float4 b0 = *(const float4*)(x_hf + base);
        float4 b1 = *(const float4*)(x_hf + base + 4);
        *(float4*)&xs[0][c][i0] = a0; *(float4*)&xs[0][c][i0 + 4] = a1;
        *(float4*)&xs[1][c][i0] = b0; *(float4*)&xs[1][c][i0 + 4] = b1;
    }
    __syncthreads();

    int lane = tid & 63, wv = tid >> 6;
    int rloc = wv * 16 + (lane & 15);      // A-fragment row (local)
    int k0 = (lane >> 4) * 8;              // A/B fragment k start
    int g = lane >> 4;                     // C-layout row group
    const float* wts[2] = { w_in, w_qk };

#pragma unroll
    for (int p = 0; p < 2; ++p) {          // p=0: lf/w_in, p=1: hf/w_qk
        // A fragment: transpose-read from LDS, cvt to bf16
        short8v afrag;
#pragma unroll
        for (int j = 0; j < 8; ++j)
            afrag[j] = (short)f2bf(xs[p][k0 + j][rloc]);

        f32x4 acc[16];
#pragma unroll
        for (int ct = 0; ct < 16; ++ct)
#pragma unroll
            for (int r = 0; r < 4; ++r) acc[ct][r] = 0.f;

        const float* W = wts[p];
#pragma unroll
        for (int ct = 0; ct < 16; ++ct) {
            const float* wp = W + (ct * 16 + (lane & 15)) * 32 + k0;
            float4 w0 = *(const float4*)wp;
            float4 w1 = *(const float4*)(wp + 4);
            short8v bfrag;
            bfrag[0] = (short)f2bf(w0.x); bfrag[1] = (short)f2bf(w0.y);
            bfrag[2] = (short)f2bf(w0.z); bfrag[3] = (short)f2bf(w0.w);
            bfrag[4] = (short)f2bf(w1.x); bfrag[5] = (short)f2bf(w1.y);
            bfrag[6] = (short)f2bf(w1.z); bfrag[7] = (short)f2bf(w1.w);
            acc[ct] = __builtin_amdgcn_mfma_f32_16x16x32_bf16(afrag, bfrag, acc[ct], 0, 0, 0);
        }

        // LayerNorm stats per row (C layout: col=lane&15, row=g*4+r)
        float s[4] = {0.f, 0.f, 0.f, 0.f}, q[4] = {0.f, 0.f, 0.f, 0.f};
#pragma unroll
        for (int ct = 0; ct < 16; ++ct)
#pragma unroll
            for (int r = 0; r < 4; ++r) {
                float v = acc[ct][r];
                s[r] += v; q[r] += v * v;
            }
#pragma unroll
        for (int off = 8; off; off >>= 1)
#pragma unroll
            for (int r = 0; r < 4; ++r) {
                s[r] += __shfl_xor(s[r], off);
                q[r] += __shfl_xor(q[r], off);
            }
        float mu[4], rs[4];
#pragma unroll
        for (int r = 0; r < 4; ++r) {
            mu[r] = s[r] * (1.f / 256.f);
            rs[r] = rsqrtf(q[r] * (1.f / 256.f) - mu[r] * mu[r] + 1e-5f);
        }

        // write out
#pragma unroll
        for (int ct = 0; ct < 16; ++ct) {
            int col = ct * 16 + (lane & 15);
            float gg = ln_g[col], bv = ln_b[col];
#pragma unroll
            for (int r = 0; r < 4; ++r) {
                int row = m0 + wv * 16 + g * 4 + r;
                float v = acc[ct][r];
                float lnv = (v - mu[r]) * rs[r] * gg + bv;
                size_t o = (size_t)row * 256 + col;
                if (p == 0) {
                    epi_tok[o] = v;
                    q_b[o] = f2bf(lnv);
                } else {
                    kv_b[o] = f2bf(v);
                    k_b[o] = f2bf(lnv);
                }
            }
        }
    }
}

// ---------------------------------------------------------------------------
// K2: bf16 MFMA GEMM, 128x128 tile, 4 waves, BK=32.
// OUT[m,j] = act( sum_k A[m,k]*W[j,k] (+RES) )
// OUTMAP 0: row-major [M,N].  OUTMAP 1: QKV head layout (bn,h,l,d), fp32.
// ---------------------------------------------------------------------------
template <int OUTMAP, bool RELU, bool OBF16>
__global__ __launch_bounds__(256) void gemm_mfma(
    const unsigned short* __restrict__ A0, const unsigned short* __restrict__ A1,
    const unsigned short* __restrict__ A2, const unsigned short* __restrict__ Wb,
    void* __restrict__ OUTv, const float* __restrict__ RES,
    int K, int N)
{
    int z = blockIdx.z;
    const unsigned short* A = (z == 0) ? A0 : (z == 1) ? A1 : A2;
    const unsigned short* W = Wb + (size_t)z * 65536;

    __shared__ unsigned short As[128 * 32];
    __shared__ unsigned short Ws[128 * 32];

    int tid = threadIdx.x;
    int lane = tid & 63, wid = tid >> 6;
    int wm = wid >> 1, wn = wid & 1;
    int m0 = blockIdx.x * 128, n0 = blockIdx.y * 128;

    f32x4 acc[4][4];
#pragma unroll
    for (int i = 0; i < 4; ++i)
#pragma unroll
        for (int j = 0; j < 4; ++j)
#pragma unroll
            for (int r = 0; r < 4; ++r) acc[i][j][r] = 0.f;

    int rA = lane & 15, k8r = lane >> 4;

    for (int kc = 0; kc < K; kc += 32) {
#pragma unroll
        for (int c = 0; c < 2; ++c) {
            int i = c * 256 + tid;
            int row = i >> 2, k8 = i & 3;
            short8v va = *(const short8v*)(A + (size_t)(m0 + row) * K + kc + k8 * 8);
            short8v vw = *(const short8v*)(W + (size_t)(n0 + row) * K + kc + k8 * 8);
            *(short8v*)&As[i * 8] = va;
            *(short8v*)&Ws[i * 8] = vw;
        }
        __syncthreads();

        short8v a[4], b[4];
#pragma unroll
        for (int mi = 0; mi < 4; ++mi)
            a[mi] = *(const short8v*)&As[(wm * 64 + mi * 16 + rA) * 32 + k8r * 8];
#pragma unroll
        for (int ni = 0; ni < 4; ++ni)
            b[ni] = *(const short8v*)&Ws[(wn * 64 + ni * 16 + rA) * 32 + k8r * 8];
#pragma unroll
        for (int mi = 0; mi < 4; ++mi)
#pragma unroll
            for (int ni = 0; ni < 4; ++ni)
                acc[mi][ni] = __builtin_amdgcn_mfma_f32_16x16x32_bf16(
                    a[mi], b[ni], acc[mi][ni], 0, 0, 0);
        __syncthreads();
    }

#pragma unroll
    for (int mi = 0; mi < 4; ++mi) {
#pragma unroll
        for (int ni = 0; ni < 4; ++ni) {
#pragma unroll
            for (int r = 0; r < 4; ++r) {
                int row = m0 + wm * 64 + mi * 16 + (lane >> 4) * 4 + r;
                int col = n0 + wn * 64 + ni * 16 + (lane & 15);
                float v = acc[mi][ni][r];
                if (RES) v += RES[(size_t)row * N + col];
                if (RELU) v = fmaxf(v, 0.f);
                if (OUTMAP == 0) {
                    if (OBF16)
                        ((unsigned short*)OUTv)[(size_t)row * N + col] = f2bf(v);
                    else
                        ((float*)OUTv)[(size_t)row * N + col] = v;
                } else {
                    int l = row & 1023, bn = row >> 10;   // bn-major rows
                    int h = col >> 5, d = col & 31;
                    ((float*)OUTv)[(size_t)z * 2097152 +
                                   ((bn * 8 + h) * 1024 + l) * 32 + d] = v;
                }
            }
        }
    }
}

// ---------------------------------------------------------------------------
// K3: local-window attention, block per (bh, qv): 32 queries, 7 K/V rows in LDS.
// Writes ctx as bf16, layout row-major with m = bn*1024 + l.
// ---------------------------------------------------------------------------
__global__ __launch_bounds__(256) void attn_kernel(
    const float* __restrict__ Qb, const float* __restrict__ Kb,
    const float* __restrict__ Vb, unsigned short* __restrict__ ctx)
{
    int bh = blockIdx.x >> 5;       // 0..63  (bn*8+h)
    int qv = blockIdx.x & 31;
    int tid = threadIdx.x;

    __shared__ float Ks[7][32][36];
    __shared__ float Vs[7][32][36];

#pragma unroll
    for (int it = 0; it < 7; ++it) {
        int idx = it * 256 + tid;
        int dv = idx >> 8;
        int rem = idx & 255;
        int kw = rem >> 3, c = (rem & 7) * 4;
        int kvr = qv - 3 + dv;
        int kvc = min(max(kvr, 0), 31);
        size_t base = ((size_t)bh * 1024 + kvc * 32 + kw) * 32 + c;
        *(float4*)&Ks[dv][kw][c] = *(const float4*)(Kb + base);
        *(float4*)&Vs[dv][kw][c] = *(const float4*)(Vb + base);
    }

    int qq = tid >> 3, t = tid & 7;
    int q = qv * 32 + qq;

    float4 qreg[8];
    {
        const float4* qp = (const float4*)(Qb + ((size_t)bh * 1024 + q) * 32);
#pragma unroll
        for (int d4 = 0; d4 < 8; ++d4) qreg[d4] = qp[d4];
    }
    __syncthreads();

    float s[7];
    int kwj[7], dvj[7];
    bool val[7];
#pragma unroll
    for (int jj = 0; jj < 7; ++jj) {
        int j = t + 8 * jj;
        int dv = j / 7, dw = j % 7;
        int kvr = qv - 3 + dv, kwr = qq - 3 + dw;
        val[jj] = (j < 49) && (kvr >= 0) && (kvr < 32) && (kwr >= 0) && (kwr < 32);
        dvj[jj] = min(dv, 6);
        kwj[jj] = kwr & 31;
        s[jj] = 0.f;
    }

#pragma unroll
    for (int d4 = 0; d4 < 8; ++d4) {
        float4 qv4 = qreg[d4];
#pragma unroll
        for (int jj = 0; jj < 7; ++jj) {
            float4 k4 = *(const float4*)&Ks[dvj[jj]][kwj[jj]][d4 * 4];
            s[jj] += qv4.x * k4.x + qv4.y * k4.y + qv4.z * k4.z + qv4.w * k4.w;
        }
    }

    const float scale = 0.17677669529663687f;
    float mx = -1e30f;
#pragma unroll
    for (int jj = 0; jj < 7; ++jj) {
        s[jj] = val[jj] ? s[jj] * scale : -1e30f;
        mx = fmaxf(mx, s[jj]);
    }
    mx = fmaxf(mx, __shfl_xor(mx, 4));
    mx = fmaxf(mx, __shfl_xor(mx, 2));
    mx = fmaxf(mx, __shfl_xor(mx, 1));

    float e[7], sum = 0.f;
#pragma unroll
    for (int jj = 0; jj < 7; ++jj) { e[jj] = __expf(s[jj] - mx); sum += e[jj]; }
    sum += __shfl_xor(sum, 4);
    sum += __shfl_xor(sum, 2);
    sum += __shfl_xor(sum, 1);
    float inv = 1.f / sum;

    f32x4 acc[8];
#pragma unroll
    for (int d4 = 0; d4 < 8; ++d4)
#pragma unroll
        for (int i = 0; i < 4; ++i) acc[d4][i] = 0.f;

#pragma unroll
    for (int jj = 0; jj < 7; ++jj) {
        float p = e[jj] * inv;
#pragma unroll
        for (int d4 = 0; d4 < 8; ++d4) {
            float4 v4 = *(const float4*)&Vs[dvj[jj]][kwj[jj]][d4 * 4];
            acc[d4][0] += p * v4.x; acc[d4][1] += p * v4.y;
            acc[d4][2] += p * v4.z; acc[d4][3] += p * v4.w;
        }
    }

#pragma unroll
    for (int off = 4; off; off >>= 1) {
#pragma unroll
        for (int d4 = 0; d4 < 8; ++d4) {
#pragma unroll
            for (int i = 0; i < 4; ++i)
                acc[d4][i] += __shfl_xor(acc[d4][i], off);
        }
    }

    {
        int bn = bh >> 3, h = bh & 7;
        unsigned short* dst = ctx + ((size_t)bn * 1024 + q) * 256 + h * 32 + t * 4;
        ushort4 u;
        u.x = f2bf(acc[t][0]); u.y = f2bf(acc[t][1]);
        u.z = f2bf(acc[t][2]); u.w = f2bf(acc[t][3]);
        *(ushort4*)dst = u;
    }
}

// ---------------------------------------------------------------------------
// K5: LayerNorm over E=256, output bf16
// ---------------------------------------------------------------------------
__global__ __launch_bounds__(256) void ln_kernel(
    const float* __restrict__ X, const float* __restrict__ g,
    const float* __restrict__ b, unsigned short* __restrict__ Y)
{
    int m = blockIdx.x;
    int e = threadIdx.x;
    float v = X[(size_t)m * 256 + e];
    float s = v, sq = v * v;
    for (int off = 32; off; off >>= 1) {
        s += __shfl_xor(s, off);
        sq += __shfl_xor(sq, off);
    }
    __shared__ float s4[4], q4[4];
    int wv = e >> 6;
    if ((e & 63) == 0) { s4[wv] = s; q4[wv] = sq; }
    __syncthreads();
    float S = s4[0] + s4[1] + s4[2] + s4[3];
    float SQ = q4[0] + q4[1] + q4[2] + q4[3];
    float mu = S * (1.f / 256.f);
    float rs = rsqrtf(SQ * (1.f / 256.f) - mu * mu + 1e-5f);
    Y[(size_t)m * 256 + e] = f2bf((v - mu) * rs * g[e] + b[e]);
}

// ---------------------------------------------------------------------------
// K8: final E=256 -> C=32 projection with transposed store (fp32)
// rows m = bn*1024 + l
// ---------------------------------------------------------------------------
__global__ __launch_bounds__(256) void final_out_kernel(
    const float* __restrict__ A, const float* __restrict__ Wo,
    float* __restrict__ out)
{
    __shared__ float As[8][256];
    int m0 = blockIdx.x * 8;
    int tid = threadIdx.x;
#pragma unroll
    for (int i = 0; i < 8; ++i) {
        int idx = tid + i * 256;
        As[idx >> 8][idx & 255] = A[(size_t)(m0 + (idx >> 8)) * 256 + (idx & 255)];
    }
    __syncthreads();
    int r = tid >> 5, c = tid & 31;
    const float4* wrow = (const float4*)(Wo + c * 256);
    const float4* arow = (const float4*)(&As[r][0]);
    float acc = 0.f;
#pragma unroll
    for (int e4 = 0; e4 < 64; ++e4) {
        float4 a = arow[e4];
        float4 w = wrow[e4];
        acc += a.x * w.x + a.y * w.y + a.z * w.z + a.w * w.w;
    }
    int m = m0 + r;
    int bn = m >> 10, l = m & 1023;
    int b = bn >> 2, n = bn & 3;
    int v = l >> 5, w = l & 31;
    out[(((b * 32 + c) * 4 + n) * 32 + v) * 32 + w] = acc;
}

// ---------------------------------------------------------------------------
extern "C" void kernel_launch(void* const* d_in, const int* in_sizes, int n_in,
                              void* d_out, int out_size, void* d_ws, size_t ws_size,
                              hipStream_t stream) {
    const float* x_lf       = (const float*)d_in[0];
    const float* x_hf       = (const float*)d_in[1];
    const float* w_in       = (const float*)d_in[2];
    const float* w_qk       = (const float*)d_in[3];
    const float* ln_g       = (const float*)d_in[4];
    const float* ln_b       = (const float*)d_in[5];
    const float* in_proj_w  = (const float*)d_in[6];
    const float* out_proj_w = (const float*)d_in[7];
    const float* ln2_g      = (const float*)d_in[8];
    const float* ln2_b      = (const float*)d_in[9];
    const float* ff_w1      = (const float*)d_in[10];
    const float* ff_w2      = (const float*)d_in[11];
    const float* w_out      = (const float*)d_in[12];
    float* out = (float*)d_out;

    char* w = (char*)d_ws;
    float* epi_tok  = (float*)(w);                       // 8 MB fp32 [8192,256]
    float* Qb       = (float*)(w + (8u  << 20));         // 8 MB (bn,h,l,d)
    float* Kb       = (float*)(w + (16u << 20));
    float* Vb       = (float*)(w + (24u << 20));
    unsigned short* q_b    = (unsigned short*)(w + (32u << 20));
    unsigned short* k_b    = (unsigned short*)(w + (36u << 20));
    unsigned short* kv_b   = (unsigned short*)(w + (40u << 20));
    unsigned short* ctx_b  = (unsigned short*)(w + (44u << 20));
    unsigned short* ffin_b = (unsigned short*)(w + (48u << 20));
    unsigned short* ffh_b  = (unsigned short*)(w + (52u << 20));  // 8 MB [8192,512]
    unsigned short* wqkv_b = (unsigned short*)(w + (60u << 20));
    unsigned short* wop_b  = (unsigned short*)(w + (61u << 20));
    unsigned short* wff1_b = (unsigned short*)(w + (62u << 20));
    unsigned short* wff2_b = (unsigned short*)(w + (63u << 20));

    // 0. weights -> bf16
    convw_kernel<<<512, 256, 0, stream>>>(in_proj_w, out_proj_w, ff_w1, ff_w2,
                                          wqkv_b, wop_b, wff1_b, wff2_b);
    // 1. gather + input proj (MFMA) + dual LN
    embed_ln_mfma<<<128, 256, 0, stream>>>(x_lf, x_hf, w_in, w_qk, ln_g, ln_b,
                                           epi_tok, kv_b, q_b, k_b);
    // 2. QKV projection: z 0=Q(q_b) 1=K(k_b) 2=V(kv_b) -> (bn,h,l,d) fp32
    gemm_mfma<1, false, false><<<dim3(64, 2, 3), 256, 0, stream>>>(
        q_b, k_b, kv_b, wqkv_b, (void*)Qb, nullptr, 256, 256);
    // 3. local-window attention -> ctx bf16
    attn_kernel<<<2048, 256, 0, stream>>>(Qb, Kb, Vb, ctx_b);
    // 4. out_proj + residual
    gemm_mfma<0, false, false><<<dim3(64, 2, 1), 256, 0, stream>>>(
        ctx_b, ctx_b, ctx_b, wop_b, (void*)epi_tok, epi_tok, 256, 256);
    // 5. LN2 -> bf16
    ln_kernel<<<8192, 256, 0, stream>>>(epi_tok, ln2_g, ln2_b, ffin_b);
    // 6. FF1 + ReLU -> bf16 [8192,512]
    gemm_mfma<0, true, true><<<dim3(64, 4, 1), 256, 0, stream>>>(
        ffin_b, ffin_b, ffin_b, wff1_b, (void*)ffh_b, nullptr, 256, 512);
    // 7. FF2 + residual
    gemm_mfma<0, false, false><<<dim3(64, 2, 1), 256, 0, stream>>>(
        ffh_b, ffh_b, ffh_b, wff2_b, (void*)epi_tok, epi_tok, 512, 256);
    // 8. final projection + transposed store
    final_out_kernel<<<1024, 256, 0, stream>>>(epi_tok, w_out, out);
}

// Round 4
// 106.429 us; speedup vs baseline: 3.3609x; 1.6185x over previous
//
#include <hip/hip_runtime.h>
#include <hip/hip_bf16.h>

// Problem constants: B=2,C=32,N=4,V=32,W=32,E=256,H=8,D=32,K_H=K_W=7
// L=1024, Bn=8, M=8192.  Internal row ordering: m = bn*1024 + l  (bn-major)

typedef __attribute__((ext_vector_type(8))) short short8v;   // 8 bf16 (4 VGPR)
typedef __attribute__((ext_vector_type(4))) float f32x4;

__device__ __forceinline__ unsigned short f2bf(float x) {
    union { float f; unsigned u; } c; c.f = x;
    unsigned r = c.u + 0x7FFFu + ((c.u >> 16) & 1u);
    return (unsigned short)(r >> 16);
}
__device__ __forceinline__ float bf2f(short b) {
    union { unsigned u; float f; } c;
    c.u = ((unsigned)(unsigned short)b) << 16;
    return c.f;
}

// ---------------------------------------------------------------------------
// K0: convert the four GEMM weight matrices fp32 -> bf16 bits
// ---------------------------------------------------------------------------
__global__ __launch_bounds__(256) void convw_kernel(
    const float* __restrict__ w1, const float* __restrict__ w2,
    const float* __restrict__ w3, const float* __restrict__ w4,
    unsigned short* __restrict__ o1, unsigned short* __restrict__ o2,
    unsigned short* __restrict__ o3, unsigned short* __restrict__ o4)
{
    int i = (blockIdx.x * 256 + threadIdx.x) * 4;
    const float* src; unsigned short* dst; int off;
    if (i < 196608)      { src = w1; dst = o1; off = i; }
    else if (i < 262144) { src = w2; dst = o2; off = i - 196608; }
    else if (i < 393216) { src = w3; dst = o3; off = i - 262144; }
    else                 { src = w4; dst = o4; off = i - 393216; }
    float4 v = *(const float4*)(src + off);
    ushort4 u;
    u.x = f2bf(v.x); u.y = f2bf(v.y); u.z = f2bf(v.z); u.w = f2bf(v.w);
    *(ushort4*)(dst + off) = u;
}

// ---------------------------------------------------------------------------
// K1: fused gather + input projection (MFMA, K=32) + dual LayerNorm
// ---------------------------------------------------------------------------
__global__ __launch_bounds__(256) void embed_ln_mfma(
    const float* __restrict__ x_lf, const float* __restrict__ x_hf,
    const float* __restrict__ w_in, const float* __restrict__ w_qk,
    const float* __restrict__ ln_g, const float* __restrict__ ln_b,
    float* __restrict__ epi_tok, unsigned short* __restrict__ kv_b,
    unsigned short* __restrict__ q_b, unsigned short* __restrict__ k_b)
{
    __shared__ float xs[2][32][65];

    int m0 = blockIdx.x * 64;
    int bn = m0 >> 10, l0 = m0 & 1023;
    int bb = bn >> 2, nn = bn & 3;
    int tid = threadIdx.x;

    {
        int c = tid >> 3, i0 = (tid & 7) * 8;
        size_t base = (size_t)bb * 131072 + (size_t)c * 4096 + nn * 1024 + l0 + i0;
        float4 a0 = *(const float4*)(x_lf + base);
        float4 a1 = *(const float4*)(x_lf + base + 4);
        float4 b0 = *(const float4*)(x_hf + base);
        float4 b1 = *(const float4*)(x_hf + base + 4);
        *(float4*)&xs[0][c][i0] = a0; *(float4*)&xs[0][c][i0 + 4] = a1;
        *(float4*)&xs[1][c][i0] = b0; *(float4*)&xs[1][c][i0 + 4] = b1;
    }
    __syncthreads();

    int lane = tid & 63, wv = tid >> 6;
    int rloc = wv * 16 + (lane & 15);
    int k0 = (lane >> 4) * 8;
    int g = lane >> 4;
    const float* wts[2] = { w_in, w_qk };

#pragma unroll
    for (int p = 0; p < 2; ++p) {
        short8v afrag;
#pragma unroll
        for (int j = 0; j < 8; ++j)
            afrag[j] = (short)f2bf(xs[p][k0 + j][rloc]);

        f32x4 acc[16];
#pragma unroll
        for (int ct = 0; ct < 16; ++ct)
#pragma unroll
            for (int r = 0; r < 4; ++r) acc[ct][r] = 0.f;

        const float* W = wts[p];
#pragma unroll
        for (int ct = 0; ct < 16; ++ct) {
            const float* wp = W + (ct * 16 + (lane & 15)) * 32 + k0;
            float4 w0 = *(const float4*)wp;
            float4 w1 = *(const float4*)(wp + 4);
            short8v bfrag;
            bfrag[0] = (short)f2bf(w0.x); bfrag[1] = (short)f2bf(w0.y);
            bfrag[2] = (short)f2bf(w0.z); bfrag[3] = (short)f2bf(w0.w);
            bfrag[4] = (short)f2bf(w1.x); bfrag[5] = (short)f2bf(w1.y);
            bfrag[6] = (short)f2bf(w1.z); bfrag[7] = (short)f2bf(w1.w);
            acc[ct] = __builtin_amdgcn_mfma_f32_16x16x32_bf16(afrag, bfrag, acc[ct], 0, 0, 0);
        }

        float s[4] = {0.f, 0.f, 0.f, 0.f}, q[4] = {0.f, 0.f, 0.f, 0.f};
#pragma unroll
        for (int ct = 0; ct < 16; ++ct)
#pragma unroll
            for (int r = 0; r < 4; ++r) {
                float v = acc[ct][r];
                s[r] += v; q[r] += v * v;
            }
#pragma unroll
        for (int off = 8; off; off >>= 1)
#pragma unroll
            for (int r = 0; r < 4; ++r) {
                s[r] += __shfl_xor(s[r], off);
                q[r] += __shfl_xor(q[r], off);
            }
        float mu[4], rs[4];
#pragma unroll
        for (int r = 0; r < 4; ++r) {
            mu[r] = s[r] * (1.f / 256.f);
            rs[r] = rsqrtf(q[r] * (1.f / 256.f) - mu[r] * mu[r] + 1e-5f);
        }

#pragma unroll
        for (int ct = 0; ct < 16; ++ct) {
            int col = ct * 16 + (lane & 15);
            float gg = ln_g[col], bv = ln_b[col];
#pragma unroll
            for (int r = 0; r < 4; ++r) {
                int row = m0 + wv * 16 + g * 4 + r;
                float v = acc[ct][r];
                float lnv = (v - mu[r]) * rs[r] * gg + bv;
                size_t o = (size_t)row * 256 + col;
                if (p == 0) {
                    epi_tok[o] = v;
                    q_b[o] = f2bf(lnv);
                } else {
                    kv_b[o] = f2bf(v);
                    k_b[o] = f2bf(lnv);
                }
            }
        }
    }
}

// ---------------------------------------------------------------------------
// K2: bf16 MFMA GEMM, 128x128 tile.  OUTMAP 0: row-major.  OUTMAP 1: QKV
// head layout (bn,h,l,d).  OBF16 selects bf16 output.
// ---------------------------------------------------------------------------
template <int OUTMAP, bool RELU, bool OBF16>
__global__ __launch_bounds__(256) void gemm_mfma(
    const unsigned short* __restrict__ A0, const unsigned short* __restrict__ A1,
    const unsigned short* __restrict__ A2, const unsigned short* __restrict__ Wb,
    void* __restrict__ OUTv, const float* __restrict__ RES,
    int K, int N)
{
    int z = blockIdx.z;
    const unsigned short* A = (z == 0) ? A0 : (z == 1) ? A1 : A2;
    const unsigned short* W = Wb + (size_t)z * 65536;

    __shared__ unsigned short As[128 * 32];
    __shared__ unsigned short Ws[128 * 32];

    int tid = threadIdx.x;
    int lane = tid & 63, wid = tid >> 6;
    int wm = wid >> 1, wn = wid & 1;
    int m0 = blockIdx.x * 128, n0 = blockIdx.y * 128;

    f32x4 acc[4][4];
#pragma unroll
    for (int i = 0; i < 4; ++i)
#pragma unroll
        for (int j = 0; j < 4; ++j)
#pragma unroll
            for (int r = 0; r < 4; ++r) acc[i][j][r] = 0.f;

    int rA = lane & 15, k8r = lane >> 4;

    for (int kc = 0; kc < K; kc += 32) {
#pragma unroll
        for (int c = 0; c < 2; ++c) {
            int i = c * 256 + tid;
            int row = i >> 2, k8 = i & 3;
            short8v va = *(const short8v*)(A + (size_t)(m0 + row) * K + kc + k8 * 8);
            short8v vw = *(const short8v*)(W + (size_t)(n0 + row) * K + kc + k8 * 8);
            *(short8v*)&As[i * 8] = va;
            *(short8v*)&Ws[i * 8] = vw;
        }
        __syncthreads();

        short8v a[4], b[4];
#pragma unroll
        for (int mi = 0; mi < 4; ++mi)
            a[mi] = *(const short8v*)&As[(wm * 64 + mi * 16 + rA) * 32 + k8r * 8];
#pragma unroll
        for (int ni = 0; ni < 4; ++ni)
            b[ni] = *(const short8v*)&Ws[(wn * 64 + ni * 16 + rA) * 32 + k8r * 8];
#pragma unroll
        for (int mi = 0; mi < 4; ++mi)
#pragma unroll
            for (int ni = 0; ni < 4; ++ni)
                acc[mi][ni] = __builtin_amdgcn_mfma_f32_16x16x32_bf16(
                    a[mi], b[ni], acc[mi][ni], 0, 0, 0);
        __syncthreads();
    }

#pragma unroll
    for (int mi = 0; mi < 4; ++mi) {
#pragma unroll
        for (int ni = 0; ni < 4; ++ni) {
#pragma unroll
            for (int r = 0; r < 4; ++r) {
                int row = m0 + wm * 64 + mi * 16 + (lane >> 4) * 4 + r;
                int col = n0 + wn * 64 + ni * 16 + (lane & 15);
                float v = acc[mi][ni][r];
                if (RES) v += RES[(size_t)row * N + col];
                if (RELU) v = fmaxf(v, 0.f);
                if (OUTMAP == 0) {
                    if (OBF16)
                        ((unsigned short*)OUTv)[(size_t)row * N + col] = f2bf(v);
                    else
                        ((float*)OUTv)[(size_t)row * N + col] = v;
                } else {
                    int l = row & 1023, bn = row >> 10;
                    int h = col >> 5, d = col & 31;
                    size_t o = (size_t)z * 2097152 + ((bn * 8 + h) * 1024 + l) * 32 + d;
                    if (OBF16) ((unsigned short*)OUTv)[o] = f2bf(v);
                    else       ((float*)OUTv)[o] = v;
                }
            }
        }
    }
}

// ---------------------------------------------------------------------------
// K3: local-window attention, bf16 Q/K/V, fp32 math.
// Block per (bh, qv): 32 queries, 7 K/V rows staged in LDS as bf16 (35 KB).
// ---------------------------------------------------------------------------
__global__ __launch_bounds__(256) void attn_kernel(
    const unsigned short* __restrict__ Qb, const unsigned short* __restrict__ Kb,
    const unsigned short* __restrict__ Vb, unsigned short* __restrict__ ctx)
{
    int bh = blockIdx.x >> 5;
    int qv = blockIdx.x & 31;
    int tid = threadIdx.x;

    __shared__ unsigned short Ks[7][32][40];
    __shared__ unsigned short Vs[7][32][40];

#pragma unroll
    for (int it = 0; it < 4; ++it) {
        int idx = it * 256 + tid;          // 896 short8 chunks per tensor
        if (idx < 896) {
            int dv = idx >> 7, rem = idx & 127;
            int kw = rem >> 2, c8 = (rem & 3) * 8;
            int kvc = min(max(qv - 3 + dv, 0), 31);
            size_t base = ((size_t)bh * 1024 + kvc * 32 + kw) * 32 + c8;
            *(short8v*)&Ks[dv][kw][c8] = *(const short8v*)(Kb + base);
            *(short8v*)&Vs[dv][kw][c8] = *(const short8v*)(Vb + base);
        }
    }

    int qq = tid >> 3, t = tid & 7;
    int q = qv * 32 + qq;

    float qf[32];
    {
        const short8v* qp = (const short8v*)(Qb + ((size_t)bh * 1024 + q) * 32);
#pragma unroll
        for (int i = 0; i < 4; ++i) {
            short8v v = qp[i];
#pragma unroll
            for (int j = 0; j < 8; ++j) qf[i * 8 + j] = bf2f(v[j]);
        }
    }
    __syncthreads();

    float s[7];
    int kwj[7], dvj[7];
    bool val[7];
#pragma unroll
    for (int jj = 0; jj < 7; ++jj) {
        int j = t + 8 * jj;
        int dv = j / 7, dw = j % 7;
        int kvr = qv - 3 + dv, kwr = qq - 3 + dw;
        val[jj] = (j < 49) && (kvr >= 0) && (kvr < 32) && (kwr >= 0) && (kwr < 32);
        dvj[jj] = min(dv, 6);
        kwj[jj] = kwr & 31;
    }

#pragma unroll
    for (int jj = 0; jj < 7; ++jj) {
        const unsigned short* kr = &Ks[dvj[jj]][kwj[jj]][0];
        float acc = 0.f;
#pragma unroll
        for (int i = 0; i < 4; ++i) {
            short8v k8 = *(const short8v*)(kr + i * 8);
#pragma unroll
            for (int j = 0; j < 8; ++j) acc += qf[i * 8 + j] * bf2f(k8[j]);
        }
        s[jj] = acc;
    }

    const float scale = 0.17677669529663687f;
    float mx = -1e30f;
#pragma unroll
    for (int jj = 0; jj < 7; ++jj) {
        s[jj] = val[jj] ? s[jj] * scale : -1e30f;
        mx = fmaxf(mx, s[jj]);
    }
    mx = fmaxf(mx, __shfl_xor(mx, 4));
    mx = fmaxf(mx, __shfl_xor(mx, 2));
    mx = fmaxf(mx, __shfl_xor(mx, 1));

    float e[7], sum = 0.f;
#pragma unroll
    for (int jj = 0; jj < 7; ++jj) { e[jj] = __expf(s[jj] - mx); sum += e[jj]; }
    sum += __shfl_xor(sum, 4);
    sum += __shfl_xor(sum, 2);
    sum += __shfl_xor(sum, 1);
    float inv = 1.f / sum;

    float av[32];
#pragma unroll
    for (int i = 0; i < 32; ++i) av[i] = 0.f;

#pragma unroll
    for (int jj = 0; jj < 7; ++jj) {
        float p = e[jj] * inv;
        const unsigned short* vr = &Vs[dvj[jj]][kwj[jj]][0];
#pragma unroll
        for (int i = 0; i < 4; ++i) {
            short8v v8 = *(const short8v*)(vr + i * 8);
#pragma unroll
            for (int j = 0; j < 8; ++j) av[i * 8 + j] += p * bf2f(v8[j]);
        }
    }

#pragma unroll
    for (int off = 4; off; off >>= 1)
#pragma unroll
        for (int i = 0; i < 32; ++i) av[i] += __shfl_xor(av[i], off);

    {
        int bn = bh >> 3, h = bh & 7;
        unsigned short* dst = ctx + ((size_t)bn * 1024 + q) * 256 + h * 32 + t * 4;
        ushort4 u;
        u.x = f2bf(av[t * 4 + 0]); u.y = f2bf(av[t * 4 + 1]);
        u.z = f2bf(av[t * 4 + 2]); u.w = f2bf(av[t * 4 + 3]);
        *(ushort4*)dst = u;
    }
}

// ---------------------------------------------------------------------------
// K4: out_proj + residual + LN2 fused.  Tile 64 rows x 256 cols, 4 waves.
// epi_tok updated in place (fp32); LN output -> ffin bf16.
// ---------------------------------------------------------------------------
__global__ __launch_bounds__(256) void outproj_ln_kernel(
    const unsigned short* __restrict__ ctx, const unsigned short* __restrict__ Wop,
    float* __restrict__ epi_tok, const float* __restrict__ g2,
    const float* __restrict__ b2, unsigned short* __restrict__ ffin)
{
    __shared__ unsigned short As[64 * 32];
    __shared__ unsigned short Ws[256 * 32];

    int tid = threadIdx.x, lane = tid & 63, wv = tid >> 6;
    int m0 = blockIdx.x * 64;
    int rA = lane & 15, k8r = lane >> 4, g = lane >> 4;

    f32x4 acc[16];
#pragma unroll
    for (int ct = 0; ct < 16; ++ct)
#pragma unroll
        for (int r = 0; r < 4; ++r) acc[ct][r] = 0.f;

    for (int kc = 0; kc < 256; kc += 32) {
        {
            int row = tid >> 2, k8 = (tid & 3) * 8;
            *(short8v*)&As[row * 32 + k8] =
                *(const short8v*)(ctx + (size_t)(m0 + row) * 256 + kc + k8);
        }
#pragma unroll
        for (int c = 0; c < 4; ++c) {
            int i = c * 256 + tid;
            int row = i >> 2, k8 = (i & 3) * 8;
            *(short8v*)&Ws[row * 32 + k8] =
                *(const short8v*)(Wop + (size_t)row * 256 + kc + k8);
        }
        __syncthreads();
        short8v a = *(const short8v*)&As[(wv * 16 + rA) * 32 + k8r * 8];
#pragma unroll
        for (int ct = 0; ct < 16; ++ct) {
            short8v b = *(const short8v*)&Ws[(ct * 16 + rA) * 32 + k8r * 8];
            acc[ct] = __builtin_amdgcn_mfma_f32_16x16x32_bf16(a, b, acc[ct], 0, 0, 0);
        }
        __syncthreads();
    }

    float s[4] = {0.f, 0.f, 0.f, 0.f}, q[4] = {0.f, 0.f, 0.f, 0.f};
#pragma unroll
    for (int ct = 0; ct < 16; ++ct) {
        int col = ct * 16 + rA;
#pragma unroll
        for (int r = 0; r < 4; ++r) {
            int row = m0 + wv * 16 + g * 4 + r;
            float v = acc[ct][r] + epi_tok[(size_t)row * 256 + col];
            acc[ct][r] = v;
            s[r] += v; q[r] += v * v;
        }
    }
#pragma unroll
    for (int off = 8; off; off >>= 1)
#pragma unroll
        for (int r = 0; r < 4; ++r) {
            s[r] += __shfl_xor(s[r], off);
            q[r] += __shfl_xor(q[r], off);
        }
    float mu[4], rs[4];
#pragma unroll
    for (int r = 0; r < 4; ++r) {
        mu[r] = s[r] * (1.f / 256.f);
        rs[r] = rsqrtf(q[r] * (1.f / 256.f) - mu[r] * mu[r] + 1e-5f);
    }
#pragma unroll
    for (int ct = 0; ct < 16; ++ct) {
        int col = ct * 16 + rA;
        float gg = g2[col], bv = b2[col];
#pragma unroll
        for (int r = 0; r < 4; ++r) {
            int row = m0 + wv * 16 + g * 4 + r;
            size_t o = (size_t)row * 256 + col;
            epi_tok[o] = acc[ct][r];
            ffin[o] = f2bf((acc[ct][r] - mu[r]) * rs[r] * gg + bv);
        }
    }
}

// ---------------------------------------------------------------------------
// K6: FF2 + residual + final E->32 projection + transposed store, fused.
// Tile 64 rows x 256 cols (K=512), then per-wave transpose via LDS and a
// second MFMA chain against w_out (fp32, cvt in-register).
// ---------------------------------------------------------------------------
__global__ __launch_bounds__(256) void ff2_final_kernel(
    const unsigned short* __restrict__ ffh, const unsigned short* __restrict__ W2,
    const float* __restrict__ epi_tok, const float* __restrict__ w_out,
    float* __restrict__ out)
{
    __shared__ unsigned short As[64 * 32];
    __shared__ unsigned short Ws[256 * 32];
    __shared__ unsigned short Ts[64 * 264];

    int tid = threadIdx.x, lane = tid & 63, wv = tid >> 6;
    int m0 = blockIdx.x * 64;
    int rA = lane & 15, k8r = lane >> 4, g = lane >> 4;

    f32x4 acc[16];
#pragma unroll
    for (int ct = 0; ct < 16; ++ct)
#pragma unroll
        for (int r = 0; r < 4; ++r) acc[ct][r] = 0.f;

    for (int kc = 0; kc < 512; kc += 32) {
        {
            int row = tid >> 2, k8 = (tid & 3) * 8;
            *(short8v*)&As[row * 32 + k8] =
                *(const short8v*)(ffh + (size_t)(m0 + row) * 512 + kc + k8);
        }
#pragma unroll
        for (int c = 0; c < 4; ++c) {
            int i = c * 256 + tid;
            int row = i >> 2, k8 = (i & 3) * 8;
            *(short8v*)&Ws[row * 32 + k8] =
                *(const short8v*)(W2 + (size_t)row * 512 + kc + k8);
        }
        __syncthreads();
        short8v a = *(const short8v*)&As[(wv * 16 + rA) * 32 + k8r * 8];
#pragma unroll
        for (int ct = 0; ct < 16; ++ct) {
            short8v b = *(const short8v*)&Ws[(ct * 16 + rA) * 32 + k8r * 8];
            acc[ct] = __builtin_amdgcn_mfma_f32_16x16x32_bf16(a, b, acc[ct], 0, 0, 0);
        }
        __syncthreads();
    }

    // residual add, store T = epi_token_final into LDS as bf16
#pragma unroll
    for (int ct = 0; ct < 16; ++ct) {
        int col = ct * 16 + rA;
#pragma unroll
        for (int r = 0; r < 4; ++r) {
            int row = m0 + wv * 16 + g * 4 + r;
            float v = acc[ct][r] + epi_tok[(size_t)row * 256 + col];
            Ts[(wv * 16 + g * 4 + r) * 264 + col] = f2bf(v);
        }
    }
    __syncthreads();

    int bn = m0 >> 10, l0 = m0 & 1023;
    int bb = bn >> 2, nn = bn & 3;

#pragma unroll
    for (int ct2 = 0; ct2 < 2; ++ct2) {
        f32x4 a2;
#pragma unroll
        for (int r = 0; r < 4; ++r) a2[r] = 0.f;
#pragma unroll
        for (int ks = 0; ks < 8; ++ks) {
            short8v af = *(const short8v*)&Ts[(wv * 16 + rA) * 264 + ks * 32 + k8r * 8];
            const float* wp = w_out + (ct2 * 16 + rA) * 256 + ks * 32 + k8r * 8;
            float4 w0 = *(const float4*)wp;
            float4 w1 = *(const float4*)(wp + 4);
            short8v bf;
            bf[0] = (short)f2bf(w0.x); bf[1] = (short)f2bf(w0.y);
            bf[2] = (short)f2bf(w0.z); bf[3] = (short)f2bf(w0.w);
            bf[4] = (short)f2bf(w1.x); bf[5] = (short)f2bf(w1.y);
            bf[6] = (short)f2bf(w1.z); bf[7] = (short)f2bf(w1.w);
            a2 = __builtin_amdgcn_mfma_f32_16x16x32_bf16(af, bf, a2, 0, 0, 0);
        }
        int c = ct2 * 16 + rA;
        int l = l0 + wv * 16 + g * 4;
        float4 st; st.x = a2[0]; st.y = a2[1]; st.z = a2[2]; st.w = a2[3];
        *(float4*)(out + ((size_t)(bb * 32 + c) * 4 + nn) * 1024 + l) = st;
    }
}

// ---------------------------------------------------------------------------
extern "C" void kernel_launch(void* const* d_in, const int* in_sizes, int n_in,
                              void* d_out, int out_size, void* d_ws, size_t ws_size,
                              hipStream_t stream) {
    const float* x_lf       = (const float*)d_in[0];
    const float* x_hf       = (const float*)d_in[1];
    const float* w_in       = (const float*)d_in[2];
    const float* w_qk       = (const float*)d_in[3];
    const float* ln_g       = (const float*)d_in[4];
    const float* ln_b       = (const float*)d_in[5];
    const float* in_proj_w  = (const float*)d_in[6];
    const float* out_proj_w = (const float*)d_in[7];
    const float* ln2_g      = (const float*)d_in[8];
    const float* ln2_b      = (const float*)d_in[9];
    const float* ff_w1      = (const float*)d_in[10];
    const float* ff_w2      = (const float*)d_in[11];
    const float* w_out      = (const float*)d_in[12];
    float* out = (float*)d_out;

    char* w = (char*)d_ws;
    float* epi_tok         = (float*)(w);                         // 8 MB fp32
    unsigned short* Qb     = (unsigned short*)(w + (8u  << 20));  // 4 MB bf16
    unsigned short* Kb     = (unsigned short*)(w + (12u << 20));
    unsigned short* Vb     = (unsigned short*)(w + (16u << 20));
    unsigned short* q_b    = (unsigned short*)(w + (20u << 20));
    unsigned short* k_b    = (unsigned short*)(w + (24u << 20));
    unsigned short* kv_b   = (unsigned short*)(w + (28u << 20));
    unsigned short* ctx_b  = (unsigned short*)(w + (32u << 20));
    unsigned short* ffin_b = (unsigned short*)(w + (36u << 20));
    unsigned short* ffh_b  = (unsigned short*)(w + (40u << 20));  // 8 MB
    unsigned short* wqkv_b = (unsigned short*)(w + (48u << 20));
    unsigned short* wop_b  = (unsigned short*)(w + (49u << 20));
    unsigned short* wff1_b = (unsigned short*)(w + (50u << 20));
    unsigned short* wff2_b = (unsigned short*)(w + (51u << 20));

    // 0. weights -> bf16
    convw_kernel<<<512, 256, 0, stream>>>(in_proj_w, out_proj_w, ff_w1, ff_w2,
                                          wqkv_b, wop_b, wff1_b, wff2_b);
    // 1. gather + input proj (MFMA) + dual LN
    embed_ln_mfma<<<128, 256, 0, stream>>>(x_lf, x_hf, w_in, w_qk, ln_g, ln_b,
                                           epi_tok, kv_b, q_b, k_b);
    // 2. QKV projection -> bf16 (bn,h,l,d)
    gemm_mfma<1, false, true><<<dim3(64, 2, 3), 256, 0, stream>>>(
        q_b, k_b, kv_b, wqkv_b, (void*)Qb, nullptr, 256, 256);
    // 3. local-window attention -> ctx bf16
    attn_kernel<<<2048, 256, 0, stream>>>(Qb, Kb, Vb, ctx_b);
    // 4. out_proj + residual + LN2 (fused) -> epi_tok fp32, ffin bf16
    outproj_ln_kernel<<<128, 256, 0, stream>>>(ctx_b, wop_b, epi_tok,
                                               ln2_g, ln2_b, ffin_b);
    // 5. FF1 + ReLU -> bf16 [8192,512]
    gemm_mfma<0, true, true><<<dim3(64, 4, 1), 256, 0, stream>>>(
        ffin_b, ffin_b, ffin_b, wff1_b, (void*)ffh_b, nullptr, 256, 512);
    // 6. FF2 + residual + final projection + transposed store (fused)
    ff2_final_kernel<<<128, 256, 0, stream>>>(ffh_b, wff2_b, epi_tok, w_out, out);
}

// Round 5
// 97.112 us; speedup vs baseline: 3.6834x; 1.0959x over previous
//
#include <hip/hip_runtime.h>
#include <hip/hip_bf16.h>

// Problem constants: B=2,C=32,N=4,V=32,W=32,E=256,H=8,D=32,K_H=K_W=7
// L=1024, Bn=8, M=8192.  Internal row ordering: m = bn*1024 + l  (bn-major)

typedef __attribute__((ext_vector_type(8))) short short8v;   // 8 bf16 (4 VGPR)
typedef __attribute__((ext_vector_type(4))) float f32x4;

__device__ __forceinline__ unsigned short f2bf(float x) {
    union { float f; unsigned u; } c; c.f = x;
    unsigned r = c.u + 0x7FFFu + ((c.u >> 16) & 1u);
    return (unsigned short)(r >> 16);
}
__device__ __forceinline__ float bf2f(short b) {
    union { unsigned u; float f; } c;
    c.u = ((unsigned)(unsigned short)b) << 16;
    return c.f;
}

// ---------------------------------------------------------------------------
// K1: blocks 0-127: fused gather + input projection (MFMA) + dual LayerNorm.
//     blocks 128-255: fp32->bf16 conversion of the four GEMM weight matrices.
// ---------------------------------------------------------------------------
__global__ __launch_bounds__(256) void embed_conv_kernel(
    const float* __restrict__ x_lf, const float* __restrict__ x_hf,
    const float* __restrict__ w_in, const float* __restrict__ w_qk,
    const float* __restrict__ ln_g, const float* __restrict__ ln_b,
    float* __restrict__ epi_tok, unsigned short* __restrict__ kv_b,
    unsigned short* __restrict__ q_b, unsigned short* __restrict__ k_b,
    const float* __restrict__ wqkv, const float* __restrict__ wop,
    const float* __restrict__ wff1, const float* __restrict__ wff2,
    unsigned short* __restrict__ o1, unsigned short* __restrict__ o2,
    unsigned short* __restrict__ o3, unsigned short* __restrict__ o4)
{
    int tid = threadIdx.x;

    if (blockIdx.x >= 128) {
        // ---- weight conversion: 524288 floats, coalesced passes ----
        int gid = (blockIdx.x - 128) * 256 + tid;   // 0..32767
#pragma unroll
        for (int j = 0; j < 4; ++j) {
            int i = (gid + j * 32768) * 4;
            const float* src; unsigned short* dst; int off;
            if (i < 196608)      { src = wqkv; dst = o1; off = i; }
            else if (i < 262144) { src = wop;  dst = o2; off = i - 196608; }
            else if (i < 393216) { src = wff1; dst = o3; off = i - 262144; }
            else                 { src = wff2; dst = o4; off = i - 393216; }
            float4 v = *(const float4*)(src + off);
            ushort4 u;
            u.x = f2bf(v.x); u.y = f2bf(v.y); u.z = f2bf(v.z); u.w = f2bf(v.w);
            *(ushort4*)(dst + off) = u;
        }
        return;
    }

    __shared__ float xs[2][32][65];

    int m0 = blockIdx.x * 64;
    int bn = m0 >> 10, l0 = m0 & 1023;
    int bb = bn >> 2, nn = bn & 3;

    {
        int c = tid >> 3, i0 = (tid & 7) * 8;
        size_t base = (size_t)bb * 131072 + (size_t)c * 4096 + nn * 1024 + l0 + i0;
        float4 a0 = *(const float4*)(x_lf + base);
        float4 a1 = *(const float4*)(x_lf + base + 4);
        float4 b0 = *(const float4*)(x_hf + base);
        float4 b1 = *(const float4*)(x_hf + base + 4);
        *(float4*)&xs[0][c][i0] = a0; *(float4*)&xs[0][c][i0 + 4] = a1;
        *(float4*)&xs[1][c][i0] = b0; *(float4*)&xs[1][c][i0 + 4] = b1;
    }
    __syncthreads();

    int lane = tid & 63, wv = tid >> 6;
    int rloc = wv * 16 + (lane & 15);
    int k0 = (lane >> 4) * 8;
    int g = lane >> 4;
    const float* wts[2] = { w_in, w_qk };

#pragma unroll
    for (int p = 0; p < 2; ++p) {
        short8v afrag;
#pragma unroll
        for (int j = 0; j < 8; ++j)
            afrag[j] = (short)f2bf(xs[p][k0 + j][rloc]);

        f32x4 acc[16];
#pragma unroll
        for (int ct = 0; ct < 16; ++ct)
#pragma unroll
            for (int r = 0; r < 4; ++r) acc[ct][r] = 0.f;

        const float* W = wts[p];
#pragma unroll
        for (int ct = 0; ct < 16; ++ct) {
            const float* wp = W + (ct * 16 + (lane & 15)) * 32 + k0;
            float4 w0 = *(const float4*)wp;
            float4 w1 = *(const float4*)(wp + 4);
            short8v bfrag;
            bfrag[0] = (short)f2bf(w0.x); bfrag[1] = (short)f2bf(w0.y);
            bfrag[2] = (short)f2bf(w0.z); bfrag[3] = (short)f2bf(w0.w);
            bfrag[4] = (short)f2bf(w1.x); bfrag[5] = (short)f2bf(w1.y);
            bfrag[6] = (short)f2bf(w1.z); bfrag[7] = (short)f2bf(w1.w);
            acc[ct] = __builtin_amdgcn_mfma_f32_16x16x32_bf16(afrag, bfrag, acc[ct], 0, 0, 0);
        }

        float s[4] = {0.f, 0.f, 0.f, 0.f}, q[4] = {0.f, 0.f, 0.f, 0.f};
#pragma unroll
        for (int ct = 0; ct < 16; ++ct)
#pragma unroll
            for (int r = 0; r < 4; ++r) {
                float v = acc[ct][r];
                s[r] += v; q[r] += v * v;
            }
#pragma unroll
        for (int off = 8; off; off >>= 1)
#pragma unroll
            for (int r = 0; r < 4; ++r) {
                s[r] += __shfl_xor(s[r], off);
                q[r] += __shfl_xor(q[r], off);
            }
        float mu[4], rs[4];
#pragma unroll
        for (int r = 0; r < 4; ++r) {
            mu[r] = s[r] * (1.f / 256.f);
            rs[r] = rsqrtf(q[r] * (1.f / 256.f) - mu[r] * mu[r] + 1e-5f);
        }

#pragma unroll
        for (int ct = 0; ct < 16; ++ct) {
            int col = ct * 16 + (lane & 15);
            float gg = ln_g[col], bv = ln_b[col];
#pragma unroll
            for (int r = 0; r < 4; ++r) {
                int row = m0 + wv * 16 + g * 4 + r;
                float v = acc[ct][r];
                float lnv = (v - mu[r]) * rs[r] * gg + bv;
                size_t o = (size_t)row * 256 + col;
                if (p == 0) {
                    epi_tok[o] = v;
                    q_b[o] = f2bf(lnv);
                } else {
                    kv_b[o] = f2bf(v);
                    k_b[o] = f2bf(lnv);
                }
            }
        }
    }
}

// ---------------------------------------------------------------------------
// K2: bf16 MFMA GEMM, 128x128 tile.  OUTMAP 0: row-major.  OUTMAP 1: QKV
// head layout (bn,h,l,d).  OBF16 selects bf16 output.
// ---------------------------------------------------------------------------
template <int OUTMAP, bool RELU, bool OBF16>
__global__ __launch_bounds__(256) void gemm_mfma(
    const unsigned short* __restrict__ A0, const unsigned short* __restrict__ A1,
    const unsigned short* __restrict__ A2, const unsigned short* __restrict__ Wb,
    void* __restrict__ OUTv, const float* __restrict__ RES,
    int K, int N)
{
    int z = blockIdx.z;
    const unsigned short* A = (z == 0) ? A0 : (z == 1) ? A1 : A2;
    const unsigned short* W = Wb + (size_t)z * 65536;

    __shared__ unsigned short As[128 * 32];
    __shared__ unsigned short Ws[128 * 32];

    int tid = threadIdx.x;
    int lane = tid & 63, wid = tid >> 6;
    int wm = wid >> 1, wn = wid & 1;
    int m0 = blockIdx.x * 128, n0 = blockIdx.y * 128;

    f32x4 acc[4][4];
#pragma unroll
    for (int i = 0; i < 4; ++i)
#pragma unroll
        for (int j = 0; j < 4; ++j)
#pragma unroll
            for (int r = 0; r < 4; ++r) acc[i][j][r] = 0.f;

    int rA = lane & 15, k8r = lane >> 4;

    for (int kc = 0; kc < K; kc += 32) {
#pragma unroll
        for (int c = 0; c < 2; ++c) {
            int i = c * 256 + tid;
            int row = i >> 2, k8 = i & 3;
            short8v va = *(const short8v*)(A + (size_t)(m0 + row) * K + kc + k8 * 8);
            short8v vw = *(const short8v*)(W + (size_t)(n0 + row) * K + kc + k8 * 8);
            *(short8v*)&As[i * 8] = va;
            *(short8v*)&Ws[i * 8] = vw;
        }
        __syncthreads();

        short8v a[4], b[4];
#pragma unroll
        for (int mi = 0; mi < 4; ++mi)
            a[mi] = *(const short8v*)&As[(wm * 64 + mi * 16 + rA) * 32 + k8r * 8];
#pragma unroll
        for (int ni = 0; ni < 4; ++ni)
            b[ni] = *(const short8v*)&Ws[(wn * 64 + ni * 16 + rA) * 32 + k8r * 8];
#pragma unroll
        for (int mi = 0; mi < 4; ++mi)
#pragma unroll
            for (int ni = 0; ni < 4; ++ni)
                acc[mi][ni] = __builtin_amdgcn_mfma_f32_16x16x32_bf16(
                    a[mi], b[ni], acc[mi][ni], 0, 0, 0);
        __syncthreads();
    }

#pragma unroll
    for (int mi = 0; mi < 4; ++mi) {
#pragma unroll
        for (int ni = 0; ni < 4; ++ni) {
#pragma unroll
            for (int r = 0; r < 4; ++r) {
                int row = m0 + wm * 64 + mi * 16 + (lane >> 4) * 4 + r;
                int col = n0 + wn * 64 + ni * 16 + (lane & 15);
                float v = acc[mi][ni][r];
                if (RES) v += RES[(size_t)row * N + col];
                if (RELU) v = fmaxf(v, 0.f);
                if (OUTMAP == 0) {
                    if (OBF16)
                        ((unsigned short*)OUTv)[(size_t)row * N + col] = f2bf(v);
                    else
                        ((float*)OUTv)[(size_t)row * N + col] = v;
                } else {
                    int l = row & 1023, bn = row >> 10;
                    int h = col >> 5, d = col & 31;
                    size_t o = (size_t)z * 2097152 + ((bn * 8 + h) * 1024 + l) * 32 + d;
                    if (OBF16) ((unsigned short*)OUTv)[o] = f2bf(v);
                    else       ((float*)OUTv)[o] = v;
                }
            }
        }
    }
}

// ---------------------------------------------------------------------------
// K3: local-window attention, bf16 Q/K/V, fp32 math.
// Block per (bh, qv): 32 queries, 7 K/V rows staged in LDS as bf16 (35 KB).
// ---------------------------------------------------------------------------
__global__ __launch_bounds__(256) void attn_kernel(
    const unsigned short* __restrict__ Qb, const unsigned short* __restrict__ Kb,
    const unsigned short* __restrict__ Vb, unsigned short* __restrict__ ctx)
{
    int bh = blockIdx.x >> 5;
    int qv = blockIdx.x & 31;
    int tid = threadIdx.x;

    __shared__ unsigned short Ks[7][32][40];
    __shared__ unsigned short Vs[7][32][40];

#pragma unroll
    for (int it = 0; it < 4; ++it) {
        int idx = it * 256 + tid;
        if (idx < 896) {
            int dv = idx >> 7, rem = idx & 127;
            int kw = rem >> 2, c8 = (rem & 3) * 8;
            int kvc = min(max(qv - 3 + dv, 0), 31);
            size_t base = ((size_t)bh * 1024 + kvc * 32 + kw) * 32 + c8;
            *(short8v*)&Ks[dv][kw][c8] = *(const short8v*)(Kb + base);
            *(short8v*)&Vs[dv][kw][c8] = *(const short8v*)(Vb + base);
        }
    }

    int qq = tid >> 3, t = tid & 7;
    int q = qv * 32 + qq;

    float qf[32];
    {
        const short8v* qp = (const short8v*)(Qb + ((size_t)bh * 1024 + q) * 32);
#pragma unroll
        for (int i = 0; i < 4; ++i) {
            short8v v = qp[i];
#pragma unroll
            for (int j = 0; j < 8; ++j) qf[i * 8 + j] = bf2f(v[j]);
        }
    }
    __syncthreads();

    float s[7];
    int kwj[7], dvj[7];
    bool val[7];
#pragma unroll
    for (int jj = 0; jj < 7; ++jj) {
        int j = t + 8 * jj;
        int dv = j / 7, dw = j % 7;
        int kvr = qv - 3 + dv, kwr = qq - 3 + dw;
        val[jj] = (j < 49) && (kvr >= 0) && (kvr < 32) && (kwr >= 0) && (kwr < 32);
        dvj[jj] = min(dv, 6);
        kwj[jj] = kwr & 31;
    }

#pragma unroll
    for (int jj = 0; jj < 7; ++jj) {
        const unsigned short* kr = &Ks[dvj[jj]][kwj[jj]][0];
        float acc = 0.f;
#pragma unroll
        for (int i = 0; i < 4; ++i) {
            short8v k8 = *(const short8v*)(kr + i * 8);
#pragma unroll
            for (int j = 0; j < 8; ++j) acc += qf[i * 8 + j] * bf2f(k8[j]);
        }
        s[jj] = acc;
    }

    const float scale = 0.17677669529663687f;
    float mx = -1e30f;
#pragma unroll
    for (int jj = 0; jj < 7; ++jj) {
        s[jj] = val[jj] ? s[jj] * scale : -1e30f;
        mx = fmaxf(mx, s[jj]);
    }
    mx = fmaxf(mx, __shfl_xor(mx, 4));
    mx = fmaxf(mx, __shfl_xor(mx, 2));
    mx = fmaxf(mx, __shfl_xor(mx, 1));

    float e[7], sum = 0.f;
#pragma unroll
    for (int jj = 0; jj < 7; ++jj) { e[jj] = __expf(s[jj] - mx); sum += e[jj]; }
    sum += __shfl_xor(sum, 4);
    sum += __shfl_xor(sum, 2);
    sum += __shfl_xor(sum, 1);
    float inv = 1.f / sum;

    float av[32];
#pragma unroll
    for (int i = 0; i < 32; ++i) av[i] = 0.f;

#pragma unroll
    for (int jj = 0; jj < 7; ++jj) {
        float p = e[jj] * inv;
        const unsigned short* vr = &Vs[dvj[jj]][kwj[jj]][0];
#pragma unroll
        for (int i = 0; i < 4; ++i) {
            short8v v8 = *(const short8v*)(vr + i * 8);
#pragma unroll
            for (int j = 0; j < 8; ++j) av[i * 8 + j] += p * bf2f(v8[j]);
        }
    }

#pragma unroll
    for (int off = 4; off; off >>= 1)
#pragma unroll
        for (int i = 0; i < 32; ++i) av[i] += __shfl_xor(av[i], off);

    {
        int bn = bh >> 3, h = bh & 7;
        unsigned short* dst = ctx + ((size_t)bn * 1024 + q) * 256 + h * 32 + t * 4;
        ushort4 u;
        u.x = f2bf(av[t * 4 + 0]); u.y = f2bf(av[t * 4 + 1]);
        u.z = f2bf(av[t * 4 + 2]); u.w = f2bf(av[t * 4 + 3]);
        *(ushort4*)dst = u;
    }
}

// ---------------------------------------------------------------------------
// K4: out_proj + residual + LN2 fused.  Tile 32 rows x 256 cols, 4 waves.
// Wave w: row group rg=w&1 (16 rows), col half ch=w>>1 (128 cols, 8 tiles).
// ---------------------------------------------------------------------------
__global__ __launch_bounds__(256) void outproj_ln_kernel(
    const unsigned short* __restrict__ ctx, const unsigned short* __restrict__ Wop,
    float* __restrict__ epi_tok, const float* __restrict__ g2,
    const float* __restrict__ b2, unsigned short* __restrict__ ffin)
{
    __shared__ unsigned short As[32 * 32];
    __shared__ unsigned short Ws[256 * 32];
    __shared__ float part[2][2][4][4][2];   // [rg][ch][g][r][{s,q}]

    int tid = threadIdx.x, lane = tid & 63, wv = tid >> 6;
    int m0 = blockIdx.x * 32;
    int rA = lane & 15, k8r = lane >> 4, g = lane >> 4;
    int rg = wv & 1, ch = wv >> 1;

    f32x4 acc[8];
#pragma unroll
    for (int ct = 0; ct < 8; ++ct)
#pragma unroll
        for (int r = 0; r < 4; ++r) acc[ct][r] = 0.f;

    for (int kc = 0; kc < 256; kc += 32) {
        if (tid < 128) {
            int row = tid >> 2, k8 = (tid & 3) * 8;
            *(short8v*)&As[row * 32 + k8] =
                *(const short8v*)(ctx + (size_t)(m0 + row) * 256 + kc + k8);
        }
#pragma unroll
        for (int c = 0; c < 4; ++c) {
            int i = c * 256 + tid;
            int row = i >> 2, k8 = (i & 3) * 8;
            *(short8v*)&Ws[row * 32 + k8] =
                *(const short8v*)(Wop + (size_t)row * 256 + kc + k8);
        }
        __syncthreads();
        short8v a = *(const short8v*)&As[(rg * 16 + rA) * 32 + k8r * 8];
#pragma unroll
        for (int ct = 0; ct < 8; ++ct) {
            short8v b = *(const short8v*)&Ws[(ch * 128 + ct * 16 + rA) * 32 + k8r * 8];
            acc[ct] = __builtin_amdgcn_mfma_f32_16x16x32_bf16(a, b, acc[ct], 0, 0, 0);
        }
        __syncthreads();
    }

    float s[4] = {0.f, 0.f, 0.f, 0.f}, q[4] = {0.f, 0.f, 0.f, 0.f};
#pragma unroll
    for (int ct = 0; ct < 8; ++ct) {
        int col = ch * 128 + ct * 16 + rA;
#pragma unroll
        for (int r = 0; r < 4; ++r) {
            int row = m0 + rg * 16 + g * 4 + r;
            float v = acc[ct][r] + epi_tok[(size_t)row * 256 + col];
            acc[ct][r] = v;
            s[r] += v; q[r] += v * v;
        }
    }
#pragma unroll
    for (int off = 8; off; off >>= 1)
#pragma unroll
        for (int r = 0; r < 4; ++r) {
            s[r] += __shfl_xor(s[r], off);
            q[r] += __shfl_xor(q[r], off);
        }
    if (rA == 0) {
#pragma unroll
        for (int r = 0; r < 4; ++r) {
            part[rg][ch][g][r][0] = s[r];
            part[rg][ch][g][r][1] = q[r];
        }
    }
    __syncthreads();
    float mu[4], rs[4];
#pragma unroll
    for (int r = 0; r < 4; ++r) {
        float S = part[rg][0][g][r][0] + part[rg][1][g][r][0];
        float Q = part[rg][0][g][r][1] + part[rg][1][g][r][1];
        mu[r] = S * (1.f / 256.f);
        rs[r] = rsqrtf(Q * (1.f / 256.f) - mu[r] * mu[r] + 1e-5f);
    }
#pragma unroll
    for (int ct = 0; ct < 8; ++ct) {
        int col = ch * 128 + ct * 16 + rA;
        float gg = g2[col], bv = b2[col];
#pragma unroll
        for (int r = 0; r < 4; ++r) {
            int row = m0 + rg * 16 + g * 4 + r;
            size_t o = (size_t)row * 256 + col;
            epi_tok[o] = acc[ct][r];
            ffin[o] = f2bf((acc[ct][r] - mu[r]) * rs[r] * gg + bv);
        }
    }
}

// ---------------------------------------------------------------------------
// K6: FF2 + residual + final E->32 projection + transposed store, fused.
// Tile 32 rows x 256 cols (K=512); stage-2 MFMA vs w_out via LDS transpose.
// ---------------------------------------------------------------------------
__global__ __launch_bounds__(256) void ff2_final_kernel(
    const unsigned short* __restrict__ ffh, const unsigned short* __restrict__ W2,
    const float* __restrict__ epi_tok, const float* __restrict__ w_out,
    float* __restrict__ out)
{
    __shared__ unsigned short As[32 * 32];
    __shared__ unsigned short Ws[256 * 32];
    __shared__ unsigned short Ts[32 * 264];

    int tid = threadIdx.x, lane = tid & 63, wv = tid >> 6;
    int m0 = blockIdx.x * 32;
    int rA = lane & 15, k8r = lane >> 4, g = lane >> 4;
    int rg = wv & 1, ch = wv >> 1;

    f32x4 acc[8];
#pragma unroll
    for (int ct = 0; ct < 8; ++ct)
#pragma unroll
        for (int r = 0; r < 4; ++r) acc[ct][r] = 0.f;

    for (int kc = 0; kc < 512; kc += 32) {
        if (tid < 128) {
            int row = tid >> 2, k8 = (tid & 3) * 8;
            *(short8v*)&As[row * 32 + k8] =
                *(const short8v*)(ffh + (size_t)(m0 + row) * 512 + kc + k8);
        }
#pragma unroll
        for (int c = 0; c < 4; ++c) {
            int i = c * 256 + tid;
            int row = i >> 2, k8 = (i & 3) * 8;
            *(short8v*)&Ws[row * 32 + k8] =
                *(const short8v*)(W2 + (size_t)row * 512 + kc + k8);
        }
        __syncthreads();
        short8v a = *(const short8v*)&As[(rg * 16 + rA) * 32 + k8r * 8];
#pragma unroll
        for (int ct = 0; ct < 8; ++ct) {
            short8v b = *(const short8v*)&Ws[(ch * 128 + ct * 16 + rA) * 32 + k8r * 8];
            acc[ct] = __builtin_amdgcn_mfma_f32_16x16x32_bf16(a, b, acc[ct], 0, 0, 0);
        }
        __syncthreads();
    }

    // residual add; write T = final epi_token tile to LDS (bf16)
#pragma unroll
    for (int ct = 0; ct < 8; ++ct) {
        int col = ch * 128 + ct * 16 + rA;
#pragma unroll
        for (int r = 0; r < 4; ++r) {
            int lrow = rg * 16 + g * 4 + r;
            float v = acc[ct][r] + epi_tok[(size_t)(m0 + lrow) * 256 + col];
            Ts[lrow * 264 + col] = f2bf(v);
        }
    }
    __syncthreads();

    int bn = m0 >> 10, l0 = m0 & 1023;
    int bb = bn >> 2, nn = bn & 3;

    // stage 2: wave w -> rows (w&1)*16, cols (w>>1)*16 of the 32x32 output
    {
        int rw = wv & 1, cw = wv >> 1;
        f32x4 a2;
#pragma unroll
        for (int r = 0; r < 4; ++r) a2[r] = 0.f;
#pragma unroll
        for (int ks = 0; ks < 8; ++ks) {
            short8v af = *(const short8v*)&Ts[(rw * 16 + rA) * 264 + ks * 32 + k8r * 8];
            const float* wp = w_out + (cw * 16 + rA) * 256 + ks * 32 + k8r * 8;
            float4 w0 = *(const float4*)wp;
            float4 w1 = *(const float4*)(wp + 4);
            short8v bf;
            bf[0] = (short)f2bf(w0.x); bf[1] = (short)f2bf(w0.y);
            bf[2] = (short)f2bf(w0.z); bf[3] = (short)f2bf(w0.w);
            bf[4] = (short)f2bf(w1.x); bf[5] = (short)f2bf(w1.y);
            bf[6] = (short)f2bf(w1.z); bf[7] = (short)f2bf(w1.w);
            a2 = __builtin_amdgcn_mfma_f32_16x16x32_bf16(af, bf, a2, 0, 0, 0);
        }
        int c = cw * 16 + rA;
        int l = l0 + rw * 16 + g * 4;
        float4 st; st.x = a2[0]; st.y = a2[1]; st.z = a2[2]; st.w = a2[3];
        *(float4*)(out + ((size_t)(bb * 32 + c) * 4 + nn) * 1024 + l) = st;
    }
}

// ---------------------------------------------------------------------------
extern "C" void kernel_launch(void* const* d_in, const int* in_sizes, int n_in,
                              void* d_out, int out_size, void* d_ws, size_t ws_size,
                              hipStream_t stream) {
    const float* x_lf       = (const float*)d_in[0];
    const float* x_hf       = (const float*)d_in[1];
    const float* w_in       = (const float*)d_in[2];
    const float* w_qk       = (const float*)d_in[3];
    const float* ln_g       = (const float*)d_in[4];
    const float* ln_b       = (const float*)d_in[5];
    const float* in_proj_w  = (const float*)d_in[6];
    const float* out_proj_w = (const float*)d_in[7];
    const float* ln2_g      = (const float*)d_in[8];
    const float* ln2_b      = (const float*)d_in[9];
    const float* ff_w1      = (const float*)d_in[10];
    const float* ff_w2      = (const float*)d_in[11];
    const float* w_out      = (const float*)d_in[12];
    float* out = (float*)d_out;

    char* w = (char*)d_ws;
    float* epi_tok         = (float*)(w);                         // 8 MB fp32
    unsigned short* Qb     = (unsigned short*)(w + (8u  << 20));  // 4 MB bf16
    unsigned short* Kb     = (unsigned short*)(w + (12u << 20));
    unsigned short* Vb     = (unsigned short*)(w + (16u << 20));
    unsigned short* q_b    = (unsigned short*)(w + (20u << 20));
    unsigned short* k_b    = (unsigned short*)(w + (24u << 20));
    unsigned short* kv_b   = (unsigned short*)(w + (28u << 20));
    unsigned short* ctx_b  = (unsigned short*)(w + (32u << 20));
    unsigned short* ffin_b = (unsigned short*)(w + (36u << 20));
    unsigned short* ffh_b  = (unsigned short*)(w + (40u << 20));  // 8 MB
    unsigned short* wqkv_b = (unsigned short*)(w + (48u << 20));
    unsigned short* wop_b  = (unsigned short*)(w + (49u << 20));
    unsigned short* wff1_b = (unsigned short*)(w + (50u << 20));
    unsigned short* wff2_b = (unsigned short*)(w + (51u << 20));

    // 1. gather + input proj + dual LN  ||  weight fp32->bf16 conversion
    embed_conv_kernel<<<256, 256, 0, stream>>>(
        x_lf, x_hf, w_in, w_qk, ln_g, ln_b, epi_tok, kv_b, q_b, k_b,
        in_proj_w, out_proj_w, ff_w1, ff_w2, wqkv_b, wop_b, wff1_b, wff2_b);
    // 2. QKV projection -> bf16 (bn,h,l,d)
    gemm_mfma<1, false, true><<<dim3(64, 2, 3), 256, 0, stream>>>(
        q_b, k_b, kv_b, wqkv_b, (void*)Qb, nullptr, 256, 256);
    // 3. local-window attention -> ctx bf16
    attn_kernel<<<2048, 256, 0, stream>>>(Qb, Kb, Vb, ctx_b);
    // 4. out_proj + residual + LN2 (fused) -> epi_tok fp32, ffin bf16
    outproj_ln_kernel<<<256, 256, 0, stream>>>(ctx_b, wop_b, epi_tok,
                                               ln2_g, ln2_b, ffin_b);
    // 5. FF1 + ReLU -> bf16 [8192,512]
    gemm_mfma<0, true, true><<<dim3(64, 4, 1), 256, 0, stream>>>(
        ffin_b, ffin_b, ffin_b, wff1_b, (void*)ffh_b, nullptr, 256, 512);
    // 6. FF2 + residual + final projection + transposed store (fused)
    ff2_final_kernel<<<256, 256, 0, stream>>>(ffh_b, wff2_b, epi_tok, w_out, out);
}